// Round 8
// baseline (96.774 us; speedup 1.0000x reference)
//
#include <hip/hip_runtime.h>

#define T_   1024
#define B_   2
#define H_   16
#define DH   64
#define D_   1024
#define WND  32
#define KSZ  65
#define NG   32

typedef float f32x4 __attribute__((ext_vector_type(4)));
typedef __bf16 bf16x8 __attribute__((ext_vector_type(8)));
typedef __bf16 bf16x4 __attribute__((ext_vector_type(4)));
typedef unsigned short u16x4 __attribute__((ext_vector_type(4)));

__device__ __forceinline__ unsigned short f2bf(float f) {
  unsigned u = __float_as_uint(f);
  return (unsigned short)((u + 0x7fffu + ((u >> 16) & 1u)) >> 16);
}

// ---------------- cvt x,Wq,Wk,Wv,Wo -> bf16 arena; side-block: gidx ballot scan ----------------
__global__ __launch_bounds__(256) void cvt_kernel(const float* __restrict__ x,
    const float* __restrict__ wq, const float* __restrict__ wk,
    const float* __restrict__ wv, const float* __restrict__ wo,
    unsigned short* __restrict__ dst,
    const int* __restrict__ mask, int* __restrict__ gidxo, float* __restrict__ gvalo) {
  if (blockIdx.x == 6144) {  // gidx side-block: stable argsort(!mask) first NG per batch
    if (threadIdx.x < 128) {
      int b = threadIdx.x >> 6, lane = threadIdx.x & 63;
      const int* mb = mask + b * T_;
      unsigned long long lanemask = (1ull << lane) - 1ull;
      int base = 0;
      for (int c = 0; c < 16 && base < NG; ++c) {
        int t = c * 64 + lane;
        bool m = mb[t] != 0;
        unsigned long long bal = __ballot(m);
        int rank = __popcll(bal & lanemask);
        if (m && base + rank < NG) { gidxo[b*NG+base+rank] = t; gvalo[b*NG+base+rank] = 1.f; }
        base += __popcll(bal);
      }
      if (base < NG) {
        for (int c = 0; c < 16 && base < NG; ++c) {
          int t = c * 64 + lane;
          bool m = mb[t] == 0;
          unsigned long long bal = __ballot(m);
          int rank = __popcll(bal & lanemask);
          if (m && base + rank < NG) { gidxo[b*NG+base+rank] = t; gvalo[b*NG+base+rank] = 0.f; }
          base += __popcll(bal);
        }
      }
    }
    return;
  }
  int idx = (blockIdx.x * 256 + threadIdx.x) * 4;
  int r = idx >> 20;
  const float* src; int off;
  if (r < 2)       { src = x;  off = idx; }
  else if (r == 2) { src = wq; off = idx - 2 * 1048576; }
  else if (r == 3) { src = wk; off = idx - 3 * 1048576; }
  else if (r == 4) { src = wv; off = idx - 4 * 1048576; }
  else             { src = wo; off = idx - 5 * 1048576; }
  f32x4 v = *(const f32x4*)(src + off);
  u16x4 o;
  o.x = f2bf(v[0]); o.y = f2bf(v[1]); o.z = f2bf(v[2]); o.w = f2bf(v[3]);
  *(u16x4*)(dst + idx) = o;
}

// ---------------- z-fused QKV GEMM: A-tile shared, 3 B-tiles, 3 accumulator sets ----------------
// A: x bf16 [2048][1024]. B0/1/2: Wq/Wk/Wv bf16 [1024][1024]. 64x128 tile, 512 thr (8 waves 2x4).
// Q,K -> bf16 row-major [2048][1024]; V -> bf16 [b,h,d,t] via LDS-transpose epilogue.
__global__ __launch_bounds__(512, 2) void qkv_fused(const unsigned short* __restrict__ A,
    const unsigned short* __restrict__ B0, const unsigned short* __restrict__ B1,
    const unsigned short* __restrict__ B2,
    unsigned short* __restrict__ Cq, unsigned short* __restrict__ Ck,
    unsigned short* __restrict__ Cv) {
  constexpr int K = 1024;
  __shared__ __attribute__((aligned(16))) unsigned short SMEM[4096 + 3 * 8192];
  unsigned short* As = SMEM;             // [64][64] swz
  unsigned short* Bs = SMEM + 4096;      // [3][128][64] swz

  int m0 = blockIdx.x * 64, n0 = blockIdx.y * 128;
  int tid = threadIdx.x;
  int w = tid >> 6, l = tid & 63;
  int wr = w >> 2, wcq = w & 3;          // 2 x 4 wave grid, 32x32 tile per wave
  int lr = l & 15, kg = l >> 4;

  f32x4 acc[3][2][2] = {};

  for (int kt = 0; kt < K; kt += 64) {
    __syncthreads();
    {  // A: 512 chunks, 1 per thread
      int row = tid >> 3, c8 = tid & 7;
      *(bf16x8*)&As[row * 64 + ((c8 ^ (row & 7)) * 8)] =
          *(const bf16x8*)&A[(size_t)(m0 + row) * K + kt + c8 * 8];
    }
#pragma unroll
    for (int z = 0; z < 3; ++z) {
      const unsigned short* Bz = (z == 0) ? B0 : (z == 1 ? B1 : B2);
#pragma unroll
      for (int i = 0; i < 2; ++i) {
        int ci = tid + i * 512;
        int row = ci >> 3, c8 = ci & 7;
        *(bf16x8*)&Bs[z * 8192 + row * 64 + ((c8 ^ (row & 7)) * 8)] =
            *(const bf16x8*)&Bz[(size_t)(n0 + row) * K + kt + c8 * 8];
      }
    }
    __syncthreads();
#pragma unroll
    for (int kk = 0; kk < 2; ++kk) {
      int c8 = kk * 4 + kg;
      bf16x8 af[2], bfz[3][2];
#pragma unroll
      for (int mi = 0; mi < 2; ++mi) {
        int row = wr * 32 + mi * 16 + lr;
        af[mi] = *(bf16x8*)&As[row * 64 + ((c8 ^ (row & 7)) * 8)];
      }
#pragma unroll
      for (int z = 0; z < 3; ++z)
#pragma unroll
        for (int ni = 0; ni < 2; ++ni) {
          int row = wcq * 32 + ni * 16 + lr;
          bfz[z][ni] = *(bf16x8*)&Bs[z * 8192 + row * 64 + ((c8 ^ (row & 7)) * 8)];
        }
#pragma unroll
      for (int z = 0; z < 3; ++z)
#pragma unroll
        for (int mi = 0; mi < 2; ++mi)
#pragma unroll
          for (int ni = 0; ni < 2; ++ni)
            acc[z][mi][ni] = __builtin_amdgcn_mfma_f32_16x16x32_bf16(af[mi], bfz[z][ni], acc[z][mi][ni], 0, 0, 0);
    }
  }

  // epilogue: Q, K direct row-major stores
#pragma unroll
  for (int z = 0; z < 2; ++z) {
    unsigned short* C = z ? Ck : Cq;
#pragma unroll
    for (int mi = 0; mi < 2; ++mi)
#pragma unroll
      for (int ni = 0; ni < 2; ++ni) {
        int mbase = m0 + wr * 32 + mi * 16 + (l >> 4) * 4;
        int n = n0 + wcq * 32 + ni * 16 + lr;
#pragma unroll
        for (int r = 0; r < 4; ++r) {
          __bf16 v = (__bf16)acc[z][mi][ni][r];
          C[(size_t)(mbase + r) * 1024 + n] = *(unsigned short*)&v;
        }
      }
  }

  // epilogue: V via compact LDS transpose [128 n][64 m] (swz) -> coalesced [b,h,d,t]
  __syncthreads();
  char* Tb = (char*)SMEM;
#pragma unroll
  for (int mi = 0; mi < 2; ++mi)
#pragma unroll
    for (int ni = 0; ni < 2; ++ni) {
      int mb2 = wr * 32 + mi * 16 + (l >> 4) * 4;
      int nl = wcq * 32 + ni * 16 + lr;
      bf16x4 pk;
      pk[0] = (__bf16)acc[2][mi][ni][0]; pk[1] = (__bf16)acc[2][mi][ni][1];
      pk[2] = (__bf16)acc[2][mi][ni][2]; pk[3] = (__bf16)acc[2][mi][ni][3];
      *(bf16x4*)(Tb + ((nl * 128 + mb2 * 2) ^ ((nl & 7) << 4))) = pk;
    }
  __syncthreads();
  int bb = m0 >> 10, tbase = m0 & 1023;
#pragma unroll
  for (int it = 0; it < 2; ++it) {
    int ci = tid + it * 512;
    int dl = ci >> 3, tc = ci & 7;
    bf16x8 v = *(bf16x8*)(Tb + ((dl * 128 + tc * 16) ^ ((dl & 7) << 4)));
    int n = n0 + dl, hh = n >> 6, dd = n & 63;
    *(bf16x8*)&Cv[((size_t)(bb * H_ + hh) * DH + dd) * T_ + tbase + tc * 8] = v;
  }
}

// ---------------- out GEMM: C(f32 [2048][1024]) = ctx(bf16) * Wo^T, 64x128 tile ----------------
__global__ __launch_bounds__(256) void out_gemm(const unsigned short* __restrict__ A,
    const unsigned short* __restrict__ Bw, float* __restrict__ C) {
  constexpr int K = 1024;
  __shared__ __attribute__((aligned(16))) unsigned short SMEM[64 * 64 + 128 * 64];
  unsigned short* As = SMEM;
  unsigned short* Bs = SMEM + 64 * 64;

  int m0 = blockIdx.x * 64, n0 = blockIdx.y * 128;
  int tid = threadIdx.x;
  int w = tid >> 6, l = tid & 63;
  int wr = w >> 1, wc = w & 1;
  int lr = l & 15, kg = l >> 4;

  f32x4 acc[2][4] = {};

  for (int kt = 0; kt < K; kt += 64) {
    __syncthreads();
#pragma unroll
    for (int i = 0; i < 2; ++i) {
      int ci = tid + 256 * i;
      int row = ci >> 3, c8 = ci & 7;
      *(bf16x8*)&As[row * 64 + ((c8 ^ (row & 7)) * 8)] =
          *(const bf16x8*)&A[(size_t)(m0 + row) * K + kt + c8 * 8];
    }
#pragma unroll
    for (int i = 0; i < 4; ++i) {
      int ci = tid + 256 * i;
      int row = ci >> 3, c8 = ci & 7;
      *(bf16x8*)&Bs[row * 64 + ((c8 ^ (row & 7)) * 8)] =
          *(const bf16x8*)&Bw[(size_t)(n0 + row) * K + kt + c8 * 8];
    }
    __syncthreads();
#pragma unroll
    for (int kk = 0; kk < 2; ++kk) {
      int c8 = kk * 4 + kg;
      bf16x8 af[2], bfr[4];
#pragma unroll
      for (int mi = 0; mi < 2; ++mi) {
        int row = wr * 32 + mi * 16 + lr;
        af[mi] = *(bf16x8*)&As[row * 64 + ((c8 ^ (row & 7)) * 8)];
      }
#pragma unroll
      for (int ni = 0; ni < 4; ++ni) {
        int row = wc * 64 + ni * 16 + lr;
        bfr[ni] = *(bf16x8*)&Bs[row * 64 + ((c8 ^ (row & 7)) * 8)];
      }
#pragma unroll
      for (int mi = 0; mi < 2; ++mi)
#pragma unroll
        for (int ni = 0; ni < 4; ++ni)
          acc[mi][ni] = __builtin_amdgcn_mfma_f32_16x16x32_bf16(af[mi], bfr[ni], acc[mi][ni], 0, 0, 0);
    }
  }

#pragma unroll
  for (int mi = 0; mi < 2; ++mi)
#pragma unroll
    for (int ni = 0; ni < 4; ++ni) {
      int mbase = m0 + wr * 32 + mi * 16 + (l >> 4) * 4;
      int n = n0 + wc * 64 + ni * 16 + lr;
#pragma unroll
      for (int r = 0; r < 4; ++r)
        C[(size_t)(mbase + r) * 1024 + n] = acc[mi][ni][r];
    }
}

// ---------------- attention core: MFMA scores + MFMA PV, dual softmax, fused fa ----------------
// q,k: bf16 row-major [b*T][1024] (col = h*64+d). v: bf16 [b,h,d,t].
__global__ __launch_bounds__(512, 4) void attn_kernel(
    const unsigned short* __restrict__ qg, const unsigned short* __restrict__ kg_,
    const unsigned short* __restrict__ vg,
    const int* __restrict__ gidx_g, const float* __restrict__ gval_g,
    unsigned short* __restrict__ ctxb, float* __restrict__ fa) {
  int tid = threadIdx.x;
  int t0 = blockIdx.x * 32;
  int h = blockIdx.y, b = blockIdx.z;
  int lane = tid & 63, wv = tid >> 6;

  __shared__ __attribute__((aligned(16))) unsigned short QbL[32 * 64];
  __shared__ __attribute__((aligned(16))) unsigned short KbL[128 * 64];
  __shared__ __attribute__((aligned(16))) unsigned short VtL[64 * 128];
  __shared__ __attribute__((aligned(16))) unsigned short WbL[32 * 128];
  __shared__ __attribute__((aligned(16))) float Sf[32][132];
  __shared__ float m_out_s[32], invdo_s[32], rowfac_s[32];
  __shared__ int   gidx_s[32];
  __shared__ float gval_s[32];

  if (tid < 32) { gidx_s[tid] = gidx_g[b * NG + tid]; gval_s[tid] = gval_g[b * NG + tid]; }
  ((unsigned long long*)WbL)[tid] = 0ull;
  ((unsigned long long*)WbL)[tid + 512] = 0ull;
  __syncthreads();

  const unsigned short* qbh = qg + (size_t)(b * T_ + t0) * D_ + h * DH;
  const unsigned short* kbh = kg_ + (size_t)(b * T_) * D_ + h * DH;
  const unsigned short* vbh = vg + (size_t)(b * H_ + h) * DH * T_;

  if (tid < 256) {
    int r = tid >> 3, c8 = tid & 7;
    bf16x8 v = *(const bf16x8*)(qbh + (size_t)r * D_ + c8 * 8);
    *(bf16x8*)((char*)QbL + ((r * 128 + c8 * 16) ^ ((r & 7) << 4))) = v;
  }
#pragma unroll
  for (int it = 0; it < 2; ++it) {
    int fi = tid + it * 512;
    int r = fi >> 3, c8 = fi & 7;
    int col; bool valid;
    if (r < 96) { col = t0 - 32 + r; valid = (col >= 0 && col < T_); }
    else { int g = r - 96; valid = gval_s[g] > 0.f; col = valid ? gidx_s[g] : 0; }
    bf16x8 v = {};
    if (valid) v = *(const bf16x8*)(kbh + (size_t)col * D_ + c8 * 8);
    *(bf16x8*)((char*)KbL + ((r * 128 + c8 * 16) ^ ((r & 7) << 4))) = v;
  }
#pragma unroll
  for (int it = 0; it < 2; ++it) {
    int fi = tid + it * 512;
    if (fi < 768) {
      int d = fi / 12, rc = fi % 12;
      int cb = t0 - 32 + rc * 8;
      bf16x8 v = {};
      if (cb >= 0 && cb < T_) v = *(const bf16x8*)(vbh + d * T_ + cb);
      *(bf16x8*)((char*)VtL + ((d * 256 + rc * 16) ^ ((d & 7) << 4))) = v;
    }
  }
#pragma unroll
  for (int it = 0; it < 4; ++it) {
    int fi = tid + it * 512;
    int d = fi >> 5, g = fi & 31;
    unsigned short v = 0;
    if (gval_s[g] > 0.f) v = vbh[d * T_ + gidx_s[g]];
    *(unsigned short*)((char*)VtL + ((d * 256 + (96 + g) * 2) ^ ((d & 7) << 4))) = v;
  }
  __syncthreads();

  // phase 1: S = Q·K^T via MFMA
  {
    int mt = wv & 1, nq = wv >> 1;
    int lrr = lane & 15, kgl = lane >> 4;
    int arow = mt * 16 + lrr;
    f32x4 acc0 = {}, acc1 = {};
#pragma unroll
    for (int s = 0; s < 2; ++s) {
      int c = s * 4 + kgl;
      bf16x8 a = *(bf16x8*)((char*)QbL + ((arow * 128 + c * 16) ^ ((arow & 7) << 4)));
      int br0 = nq * 32 + lrr, br1 = nq * 32 + 16 + lrr;
      bf16x8 b0 = *(bf16x8*)((char*)KbL + ((br0 * 128 + c * 16) ^ ((br0 & 7) << 4)));
      bf16x8 b1 = *(bf16x8*)((char*)KbL + ((br1 * 128 + c * 16) ^ ((br1 & 7) << 4)));
      acc0 = __builtin_amdgcn_mfma_f32_16x16x32_bf16(a, b0, acc0, 0, 0, 0);
      acc1 = __builtin_amdgcn_mfma_f32_16x16x32_bf16(a, b1, acc1, 0, 0, 0);
    }
    int orow = mt * 16 + (lane >> 4) * 4;
#pragma unroll
    for (int i = 0; i < 4; ++i) {
      Sf[orow + i][nq * 32 + lrr] = acc0[i] * 0.125f;
      Sf[orow + i][nq * 32 + 16 + lrr] = acc1[i] * 0.125f;
    }
  }
  __syncthreads();

  // phase 2: per-row stats for both softmaxes
  {
    int r = tid >> 4, lg = tid & 15;
    int t_abs = t0 + r;
    int left = (t_abs - WND > 0) ? (t_abs - WND) : 0;
    int tmp = t_abs + WND + 1; if (tmp > T_) tmp = T_;
    int wl = tmp - left;
    float sv[8]; bool vld[8], vdd[8];
#pragma unroll
    for (int ii = 0; ii < 8; ++ii) {
      int c = lg + ii * 16;
      bool loc = (c >= r && c <= r + 64);
      bool glob = (c >= 96);
      float s = Sf[r][c];
      if (glob && !(gval_s[c - 96] > 0.f)) s = -1e9f;
      vld[ii] = loc || glob;
      vdd[ii] = loc ? ((c - r) < wl) : glob;
      sv[ii] = s;
    }
    float mo = -1e30f, md = -1e30f;
#pragma unroll
    for (int ii = 0; ii < 8; ++ii) {
      if (vld[ii]) mo = fmaxf(mo, sv[ii]);
      if (vdd[ii]) md = fmaxf(md, sv[ii]);
    }
#pragma unroll
    for (int o = 1; o < 16; o <<= 1) {
      mo = fmaxf(mo, __shfl_xor(mo, o, 16));
      md = fmaxf(md, __shfl_xor(md, o, 16));
    }
    float eo = 0.f, ed = 0.f;
#pragma unroll
    for (int ii = 0; ii < 8; ++ii) {
      if (vld[ii]) eo += __expf(sv[ii] - mo);
      if (vdd[ii]) ed += __expf(sv[ii] - md);
    }
#pragma unroll
    for (int o = 1; o < 16; o <<= 1) {
      eo += __shfl_xor(eo, o, 16);
      ed += __shfl_xor(ed, o, 16);
    }
    if (lg == 0) {
      m_out_s[r] = mo;
      invdo_s[r] = 1.f / eo;
      rowfac_s[r] = (eo / ed) * __expf(mo - md);
    }
  }
  __syncthreads();

  // phase 2b: scores -> out-path weights (f32 in Sf, bf16 in Wb)
  for (int idx = tid; idx < 32 * 97; idx += 512) {
    int t = idx / 97;
    int j = idx - t * 97;
    int cc = (j < KSZ) ? (t + j) : (j + 31);
    float s = Sf[t][cc];
    float wgt = __expf(s - m_out_s[t]) * invdo_s[t];
    Sf[t][cc] = wgt;
    *(unsigned short*)((char*)WbL + ((t * 256 + cc * 2) ^ ((t & 7) << 4))) = f2bf(wgt);
  }
  __syncthreads();

  // phase 3: ctx^T = V^T · W^T via MFMA
  {
    int mt = wv >> 1, nt = wv & 1;
    int lrr = lane & 15, kgl = lane >> 4;
    int arow = mt * 16 + lrr;
    int brow = nt * 16 + lrr;
    f32x4 acc = {};
#pragma unroll
    for (int s = 0; s < 4; ++s) {
      int c = s * 4 + kgl;
      bf16x8 a = *(bf16x8*)((char*)VtL + ((arow * 256 + c * 16) ^ ((arow & 7) << 4)));
      bf16x8 bb = *(bf16x8*)((char*)WbL + ((brow * 256 + c * 16) ^ ((brow & 7) << 4)));
      acc = __builtin_amdgcn_mfma_f32_16x16x32_bf16(a, bb, acc, 0, 0, 0);
    }
    int t = nt * 16 + lrr;
    int dbase = mt * 16 + (lane >> 4) * 4;
    u16x4 st;
    st.x = f2bf(acc[0]); st.y = f2bf(acc[1]); st.z = f2bf(acc[2]); st.w = f2bf(acc[3]);
    *(u16x4*)(ctxb + ((size_t)(b * T_ + t0 + t)) * D_ + h * DH + dbase) = st;
  }

  // phase 4: dense full_attn rows
  {
    int rp = tid >> 8;
    int c0 = (tid & 255) * 4;
    unsigned gm = 0;
#pragma unroll
    for (int g = 0; g < NG; ++g) {
      int gc = gidx_s[g];
      if (gval_s[g] > 0.f && gc >= c0 && gc < c0 + 4) gm |= (1u << g);
    }
#pragma unroll 2
    for (int rr = 0; rr < 16; ++rr) {
      int r = rr * 2 + rp;
      int t_abs = t0 + r;
      int left = (t_abs - WND > 0) ? (t_abs - WND) : 0;
      int tmp = t_abs + WND + 1; if (tmp > T_) tmp = T_;
      int wl = tmp - left;
      float rf = rowfac_s[r];
      f32x4 o = {0.f, 0.f, 0.f, 0.f};
      int jj0 = c0 - left;
      if (jj0 > -4 && jj0 < wl) {
#pragma unroll
        for (int e = 0; e < 4; ++e) {
          int jj = jj0 + e;
          if (jj >= 0 && jj < wl) o[e] = Sf[r][r + jj] * rf;
        }
      }
      if (gm) {
        unsigned mm = gm;
        while (mm) {
          int g = __ffs(mm) - 1; mm &= mm - 1;
          o[gidx_s[g] - c0] += Sf[r][96 + g] * rf;
        }
      }
      float* dst = fa + (((size_t)(b * H_ + h) * T_) + t_abs) * T_ + c0;
      *(f32x4*)dst = o;
    }
  }
}

extern "C" void kernel_launch(void* const* d_in, const int* in_sizes, int n_in,
                              void* d_out, int out_size, void* d_ws, size_t ws_size,
                              hipStream_t stream) {
  const float* x   = (const float*)d_in[0];
  const int* gmask = (const int*)d_in[1];
  const float* wq  = (const float*)d_in[2];
  const float* wk  = (const float*)d_in[3];
  const float* wv  = (const float*)d_in[4];
  const float* wo  = (const float*)d_in[5];

  unsigned short* arena = (unsigned short*)d_ws;
  unsigned short* xb  = arena;                       // [2048][1024] bf16
  unsigned short* wqb = arena + 2 * 1048576;
  unsigned short* wkb = arena + 3 * 1048576;
  unsigned short* wvb = arena + 4 * 1048576;
  unsigned short* wob = arena + 5 * 1048576;
  unsigned short* qb   = arena + 6 * 1048576;        // [2048][1024] bf16
  unsigned short* kb   = arena + 8 * 1048576;
  unsigned short* vtb  = arena + 10 * 1048576;       // [b,h,d,t]
  unsigned short* ctxb = arena + 12 * 1048576;       // [2048][1024] bf16
  int*   gidx = (int*)(arena + 14 * 1048576);
  float* gval = (float*)(gidx + 64);

  float* outp = (float*)d_out;
  float* fa   = outp + 2097152;

  cvt_kernel<<<dim3(6145), dim3(256), 0, stream>>>(x, wq, wk, wv, wo, xb, gmask, gidx, gval);
  qkv_fused<<<dim3(32, 8), dim3(512), 0, stream>>>(xb, wqb, wkb, wvb, qb, kb, vtb);
  attn_kernel<<<dim3(32, 16, 2), dim3(512), 0, stream>>>(qb, kb, vtb, gidx, gval, ctxb, fa);
  out_gemm<<<dim3(32, 8), dim3(256), 0, stream>>>(ctxb, wob, outp);
}

// Round 9
// 89.671 us; speedup vs baseline: 1.0792x; 1.0792x over previous
//
#include <hip/hip_runtime.h>

#define T_   1024
#define B_   2
#define H_   16
#define DH   64
#define D_   1024
#define WND  32
#define KSZ  65
#define NG   32

typedef float f32x4 __attribute__((ext_vector_type(4)));
typedef __bf16 bf16x8 __attribute__((ext_vector_type(8)));
typedef __bf16 bf16x4 __attribute__((ext_vector_type(4)));
typedef unsigned short u16x4 __attribute__((ext_vector_type(4)));

__device__ __forceinline__ unsigned short f2bf(float f) {
  unsigned u = __float_as_uint(f);
  return (unsigned short)((u + 0x7fffu + ((u >> 16) & 1u)) >> 16);
}

// async global->LDS 16B: linear LDS dest (wave-uniform base + lane*16).
__device__ __forceinline__ void gload16(const unsigned short* g, unsigned short* l) {
  __builtin_amdgcn_global_load_lds(
      (const __attribute__((address_space(1))) unsigned int*)g,
      (__attribute__((address_space(3))) unsigned int*)l, 16, 0, 0);
}

// ---------------- cvt x,Wq,Wk,Wv,Wo -> bf16 arena; side-block: gidx ballot scan ----------------
__global__ __launch_bounds__(256) void cvt_kernel(const float* __restrict__ x,
    const float* __restrict__ wq, const float* __restrict__ wk,
    const float* __restrict__ wv, const float* __restrict__ wo,
    unsigned short* __restrict__ dst,
    const int* __restrict__ mask, int* __restrict__ gidxo, float* __restrict__ gvalo) {
  if (blockIdx.x == 6144) {  // gidx side-block: stable argsort(!mask) first NG per batch
    if (threadIdx.x < 128) {
      int b = threadIdx.x >> 6, lane = threadIdx.x & 63;
      const int* mb = mask + b * T_;
      unsigned long long lanemask = (1ull << lane) - 1ull;
      int base = 0;
      for (int c = 0; c < 16 && base < NG; ++c) {
        int t = c * 64 + lane;
        bool m = mb[t] != 0;
        unsigned long long bal = __ballot(m);
        int rank = __popcll(bal & lanemask);
        if (m && base + rank < NG) { gidxo[b*NG+base+rank] = t; gvalo[b*NG+base+rank] = 1.f; }
        base += __popcll(bal);
      }
      if (base < NG) {
        for (int c = 0; c < 16 && base < NG; ++c) {
          int t = c * 64 + lane;
          bool m = mb[t] == 0;
          unsigned long long bal = __ballot(m);
          int rank = __popcll(bal & lanemask);
          if (m && base + rank < NG) { gidxo[b*NG+base+rank] = t; gvalo[b*NG+base+rank] = 0.f; }
          base += __popcll(bal);
        }
      }
    }
    return;
  }
  int idx = (blockIdx.x * 256 + threadIdx.x) * 4;
  int r = idx >> 20;
  const float* src; int off;
  if (r < 2)       { src = x;  off = idx; }
  else if (r == 2) { src = wq; off = idx - 2 * 1048576; }
  else if (r == 3) { src = wk; off = idx - 3 * 1048576; }
  else if (r == 4) { src = wv; off = idx - 4 * 1048576; }
  else             { src = wo; off = idx - 5 * 1048576; }
  f32x4 v = *(const f32x4*)(src + off);
  u16x4 o;
  o.x = f2bf(v[0]); o.y = f2bf(v[1]); o.z = f2bf(v[2]); o.w = f2bf(v[3]);
  *(u16x4*)(dst + idx) = o;
}

// ---------------- bf16 MFMA GEMM: C = A (MxK) * B^T (NxK), K=1024, BN=128 ----------------
// GLDS: global_load_lds staging (linear dest, pre-XOR source); else reg-staged.
// MODE 0: z in {0:Q,1:K} -> bf16 row-major [M][1024]; z==2: V -> bf16 [b,h,d,t] via transpose.
// MODE 1: C = f32 row-major [M][1024].
template<int MODE, int BM, bool GLDS>
__global__ __launch_bounds__(256) void gemm128(const unsigned short* __restrict__ A,
    const unsigned short* __restrict__ B0, const unsigned short* __restrict__ B1,
    const unsigned short* __restrict__ B2,
    void* __restrict__ C0v, void* __restrict__ C1v, void* __restrict__ C2v) {
  constexpr int K = 1024;
  constexpr int FM = BM / 32;
  constexpr int ACH = BM * 8 / 256;
  constexpr int WM = BM / 2;
  __shared__ __attribute__((aligned(16))) unsigned short SMEM[BM * 64 + 128 * 64];
  unsigned short* As = SMEM;
  unsigned short* Bs = SMEM + BM * 64;

  int m0 = blockIdx.x * BM, n0 = blockIdx.y * 128;
  int zz = (MODE == 0) ? blockIdx.z : 0;
  const unsigned short* Bb = (MODE == 0) ? (zz == 0 ? B0 : (zz == 1 ? B1 : B2)) : B0;

  int tid = threadIdx.x;
  int w = tid >> 6, l = tid & 63;
  int wr = w >> 1, wc = w & 1;
  int lr = l & 15, kg = l >> 4;

  f32x4 acc[FM][4] = {};

  for (int kt = 0; kt < K; kt += 64) {
    __syncthreads();
    if constexpr (GLDS) {
#pragma unroll
      for (int i = 0; i < ACH; ++i) {
        int ci = tid + 256 * i;
        int row = ci >> 3, c8 = (ci & 7) ^ (row & 7);
        gload16(A + (size_t)(m0 + row) * K + kt + c8 * 8, As + ci * 8);
      }
#pragma unroll
      for (int i = 0; i < 4; ++i) {
        int ci = tid + 256 * i;
        int row = ci >> 3, c8 = (ci & 7) ^ (row & 7);
        gload16(Bb + (size_t)(n0 + row) * K + kt + c8 * 8, Bs + ci * 8);
      }
    } else {
#pragma unroll
      for (int i = 0; i < ACH; ++i) {
        int ci = tid + 256 * i;
        int row = ci >> 3, c8 = ci & 7;
        *(bf16x8*)&As[row * 64 + ((c8 ^ (row & 7)) * 8)] =
            *(const bf16x8*)&A[(size_t)(m0 + row) * K + kt + c8 * 8];
      }
#pragma unroll
      for (int i = 0; i < 4; ++i) {
        int ci = tid + 256 * i;
        int row = ci >> 3, c8 = ci & 7;
        *(bf16x8*)&Bs[row * 64 + ((c8 ^ (row & 7)) * 8)] =
            *(const bf16x8*)&Bb[(size_t)(n0 + row) * K + kt + c8 * 8];
      }
    }
    __syncthreads();
#pragma unroll
    for (int kk = 0; kk < 2; ++kk) {
      int c8 = kk * 4 + kg;
      bf16x8 af[FM], bfr[4];
#pragma unroll
      for (int mi = 0; mi < FM; ++mi) {
        int row = wr * WM + mi * 16 + lr;
        af[mi] = *(bf16x8*)&As[row * 64 + ((c8 ^ (row & 7)) * 8)];
      }
#pragma unroll
      for (int ni = 0; ni < 4; ++ni) {
        int row = wc * 64 + ni * 16 + lr;
        bfr[ni] = *(bf16x8*)&Bs[row * 64 + ((c8 ^ (row & 7)) * 8)];
      }
#pragma unroll
      for (int mi = 0; mi < FM; ++mi)
#pragma unroll
        for (int ni = 0; ni < 4; ++ni)
          acc[mi][ni] = __builtin_amdgcn_mfma_f32_16x16x32_bf16(af[mi], bfr[ni], acc[mi][ni], 0, 0, 0);
    }
  }

  if (MODE == 1) {
    float* C = (float*)C0v;
#pragma unroll
    for (int mi = 0; mi < FM; ++mi)
#pragma unroll
      for (int ni = 0; ni < 4; ++ni) {
        int mbase = m0 + wr * WM + mi * 16 + (l >> 4) * 4;
        int n = n0 + wc * 64 + ni * 16 + lr;
#pragma unroll
        for (int r = 0; r < 4; ++r)
          C[(size_t)(mbase + r) * 1024 + n] = acc[mi][ni][r];
      }
  } else if (zz < 2) {
    unsigned short* C = (unsigned short*)(zz == 0 ? C0v : C1v);
#pragma unroll
    for (int mi = 0; mi < FM; ++mi)
#pragma unroll
      for (int ni = 0; ni < 4; ++ni) {
        int mbase = m0 + wr * WM + mi * 16 + (l >> 4) * 4;
        int n = n0 + wc * 64 + ni * 16 + lr;
#pragma unroll
        for (int r = 0; r < 4; ++r) {
          __bf16 v = (__bf16)acc[mi][ni][r];
          C[(size_t)(mbase + r) * 1024 + n] = *(unsigned short*)&v;
        }
      }
  } else {
    // V: compact LDS transpose [128][BM] (swizzled) -> coalesced [b,h,d,t] stores
    constexpr int RS = BM * 2;            // row stride bytes
    constexpr int TCH = BM / 8;           // bf16x8 chunks per row
    constexpr int NIT = 128 * TCH / 256;
    __syncthreads();
    char* Tb = (char*)SMEM;
#pragma unroll
    for (int mi = 0; mi < FM; ++mi)
#pragma unroll
      for (int ni = 0; ni < 4; ++ni) {
        int mb2 = wr * WM + mi * 16 + (l >> 4) * 4;
        int nl = wc * 64 + ni * 16 + lr;
        bf16x4 pk;
        pk[0] = (__bf16)acc[mi][ni][0]; pk[1] = (__bf16)acc[mi][ni][1];
        pk[2] = (__bf16)acc[mi][ni][2]; pk[3] = (__bf16)acc[mi][ni][3];
        *(bf16x4*)(Tb + ((nl * RS + mb2 * 2) ^ ((nl & 7) << 4))) = pk;
      }
    __syncthreads();
    unsigned short* C = (unsigned short*)C2v;
    int bb = m0 >> 10, tbase = m0 & 1023;
#pragma unroll
    for (int it = 0; it < NIT; ++it) {
      int ci = tid + 256 * it;
      int dl = ci / TCH, tc = ci % TCH;
      bf16x8 v = *(bf16x8*)(Tb + ((dl * RS + tc * 16) ^ ((dl & 7) << 4)));
      int n = n0 + dl, hh = n >> 6, dd = n & 63;
      *(bf16x8*)&C[((size_t)(bb * H_ + hh) * DH + dd) * T_ + tbase + tc * 8] = v;
    }
  }
}

// ---------------- attention core: MFMA scores + MFMA PV, dual softmax, fused fa ----------------
// q,k: bf16 row-major [b*T][1024] (col = h*64+d). v: bf16 [b,h,d,t].
__global__ __launch_bounds__(512, 4) void attn_kernel(
    const unsigned short* __restrict__ qg, const unsigned short* __restrict__ kg_,
    const unsigned short* __restrict__ vg,
    const int* __restrict__ gidx_g, const float* __restrict__ gval_g,
    unsigned short* __restrict__ ctxb, float* __restrict__ fa) {
  int tid = threadIdx.x;
  int t0 = blockIdx.x * 32;
  int h = blockIdx.y, b = blockIdx.z;
  int lane = tid & 63, wv = tid >> 6;

  __shared__ __attribute__((aligned(16))) unsigned short QbL[32 * 64];
  __shared__ __attribute__((aligned(16))) unsigned short KbL[128 * 64];
  __shared__ __attribute__((aligned(16))) unsigned short VtL[64 * 128];
  __shared__ __attribute__((aligned(16))) unsigned short WbL[32 * 128];
  __shared__ __attribute__((aligned(16))) float Sf[32][132];
  __shared__ float m_out_s[32], invdo_s[32], rowfac_s[32];
  __shared__ int   gidx_s[32];
  __shared__ float gval_s[32];

  if (tid < 32) { gidx_s[tid] = gidx_g[b * NG + tid]; gval_s[tid] = gval_g[b * NG + tid]; }
  ((unsigned long long*)WbL)[tid] = 0ull;
  ((unsigned long long*)WbL)[tid + 512] = 0ull;
  __syncthreads();

  const unsigned short* qbh = qg + (size_t)(b * T_ + t0) * D_ + h * DH;
  const unsigned short* kbh = kg_ + (size_t)(b * T_) * D_ + h * DH;
  const unsigned short* vbh = vg + (size_t)(b * H_ + h) * DH * T_;

  if (tid < 256) {
    int r = tid >> 3, c8 = tid & 7;
    bf16x8 v = *(const bf16x8*)(qbh + (size_t)r * D_ + c8 * 8);
    *(bf16x8*)((char*)QbL + ((r * 128 + c8 * 16) ^ ((r & 7) << 4))) = v;
  }
#pragma unroll
  for (int it = 0; it < 2; ++it) {
    int fi = tid + it * 512;
    int r = fi >> 3, c8 = fi & 7;
    int col; bool valid;
    if (r < 96) { col = t0 - 32 + r; valid = (col >= 0 && col < T_); }
    else { int g = r - 96; valid = gval_s[g] > 0.f; col = valid ? gidx_s[g] : 0; }
    bf16x8 v = {};
    if (valid) v = *(const bf16x8*)(kbh + (size_t)col * D_ + c8 * 8);
    *(bf16x8*)((char*)KbL + ((r * 128 + c8 * 16) ^ ((r & 7) << 4))) = v;
  }
#pragma unroll
  for (int it = 0; it < 2; ++it) {
    int fi = tid + it * 512;
    if (fi < 768) {
      int d = fi / 12, rc = fi % 12;
      int cb = t0 - 32 + rc * 8;
      bf16x8 v = {};
      if (cb >= 0 && cb < T_) v = *(const bf16x8*)(vbh + d * T_ + cb);
      *(bf16x8*)((char*)VtL + ((d * 256 + rc * 16) ^ ((d & 7) << 4))) = v;
    }
  }
#pragma unroll
  for (int it = 0; it < 4; ++it) {
    int fi = tid + it * 512;
    int d = fi >> 5, g = fi & 31;
    unsigned short v = 0;
    if (gval_s[g] > 0.f) v = vbh[d * T_ + gidx_s[g]];
    *(unsigned short*)((char*)VtL + ((d * 256 + (96 + g) * 2) ^ ((d & 7) << 4))) = v;
  }
  __syncthreads();

  // phase 1: S = Q·K^T via MFMA
  {
    int mt = wv & 1, nq = wv >> 1;
    int lrr = lane & 15, kgl = lane >> 4;
    int arow = mt * 16 + lrr;
    f32x4 acc0 = {}, acc1 = {};
#pragma unroll
    for (int s = 0; s < 2; ++s) {
      int c = s * 4 + kgl;
      bf16x8 a = *(bf16x8*)((char*)QbL + ((arow * 128 + c * 16) ^ ((arow & 7) << 4)));
      int br0 = nq * 32 + lrr, br1 = nq * 32 + 16 + lrr;
      bf16x8 b0 = *(bf16x8*)((char*)KbL + ((br0 * 128 + c * 16) ^ ((br0 & 7) << 4)));
      bf16x8 b1 = *(bf16x8*)((char*)KbL + ((br1 * 128 + c * 16) ^ ((br1 & 7) << 4)));
      acc0 = __builtin_amdgcn_mfma_f32_16x16x32_bf16(a, b0, acc0, 0, 0, 0);
      acc1 = __builtin_amdgcn_mfma_f32_16x16x32_bf16(a, b1, acc1, 0, 0, 0);
    }
    int orow = mt * 16 + (lane >> 4) * 4;
#pragma unroll
    for (int i = 0; i < 4; ++i) {
      Sf[orow + i][nq * 32 + lrr] = acc0[i] * 0.125f;
      Sf[orow + i][nq * 32 + 16 + lrr] = acc1[i] * 0.125f;
    }
  }
  __syncthreads();

  // phase 2: per-row stats for both softmaxes
  {
    int r = tid >> 4, lg = tid & 15;
    int t_abs = t0 + r;
    int left = (t_abs - WND > 0) ? (t_abs - WND) : 0;
    int tmp = t_abs + WND + 1; if (tmp > T_) tmp = T_;
    int wl = tmp - left;
    float sv[8]; bool vld[8], vdd[8];
#pragma unroll
    for (int ii = 0; ii < 8; ++ii) {
      int c = lg + ii * 16;
      bool loc = (c >= r && c <= r + 64);
      bool glob = (c >= 96);
      float s = Sf[r][c];
      if (glob && !(gval_s[c - 96] > 0.f)) s = -1e9f;
      vld[ii] = loc || glob;
      vdd[ii] = loc ? ((c - r) < wl) : glob;
      sv[ii] = s;
    }
    float mo = -1e30f, md = -1e30f;
#pragma unroll
    for (int ii = 0; ii < 8; ++ii) {
      if (vld[ii]) mo = fmaxf(mo, sv[ii]);
      if (vdd[ii]) md = fmaxf(md, sv[ii]);
    }
#pragma unroll
    for (int o = 1; o < 16; o <<= 1) {
      mo = fmaxf(mo, __shfl_xor(mo, o, 16));
      md = fmaxf(md, __shfl_xor(md, o, 16));
    }
    float eo = 0.f, ed = 0.f;
#pragma unroll
    for (int ii = 0; ii < 8; ++ii) {
      if (vld[ii]) eo += __expf(sv[ii] - mo);
      if (vdd[ii]) ed += __expf(sv[ii] - md);
    }
#pragma unroll
    for (int o = 1; o < 16; o <<= 1) {
      eo += __shfl_xor(eo, o, 16);
      ed += __shfl_xor(ed, o, 16);
    }
    if (lg == 0) {
      m_out_s[r] = mo;
      invdo_s[r] = 1.f / eo;
      rowfac_s[r] = (eo / ed) * __expf(mo - md);
    }
  }
  __syncthreads();

  // phase 2b: scores -> out-path weights (f32 in Sf, bf16 in Wb)
  for (int idx = tid; idx < 32 * 97; idx += 512) {
    int t = idx / 97;
    int j = idx - t * 97;
    int cc = (j < KSZ) ? (t + j) : (j + 31);
    float s = Sf[t][cc];
    float wgt = __expf(s - m_out_s[t]) * invdo_s[t];
    Sf[t][cc] = wgt;
    *(unsigned short*)((char*)WbL + ((t * 256 + cc * 2) ^ ((t & 7) << 4))) = f2bf(wgt);
  }
  __syncthreads();

  // phase 3: ctx^T = V^T · W^T via MFMA
  {
    int mt = wv >> 1, nt = wv & 1;
    int lrr = lane & 15, kgl = lane >> 4;
    int arow = mt * 16 + lrr;
    int brow = nt * 16 + lrr;
    f32x4 acc = {};
#pragma unroll
    for (int s = 0; s < 4; ++s) {
      int c = s * 4 + kgl;
      bf16x8 a = *(bf16x8*)((char*)VtL + ((arow * 256 + c * 16) ^ ((arow & 7) << 4)));
      bf16x8 bb = *(bf16x8*)((char*)WbL + ((brow * 256 + c * 16) ^ ((brow & 7) << 4)));
      acc = __builtin_amdgcn_mfma_f32_16x16x32_bf16(a, bb, acc, 0, 0, 0);
    }
    int t = nt * 16 + lrr;
    int dbase = mt * 16 + (lane >> 4) * 4;
    u16x4 st;
    st.x = f2bf(acc[0]); st.y = f2bf(acc[1]); st.z = f2bf(acc[2]); st.w = f2bf(acc[3]);
    *(u16x4*)(ctxb + ((size_t)(b * T_ + t0 + t)) * D_ + h * DH + dbase) = st;
  }

  // phase 4: dense full_attn rows
  {
    int rp = tid >> 8;
    int c0 = (tid & 255) * 4;
    unsigned gm = 0;
#pragma unroll
    for (int g = 0; g < NG; ++g) {
      int gc = gidx_s[g];
      if (gval_s[g] > 0.f && gc >= c0 && gc < c0 + 4) gm |= (1u << g);
    }
#pragma unroll 2
    for (int rr = 0; rr < 16; ++rr) {
      int r = rr * 2 + rp;
      int t_abs = t0 + r;
      int left = (t_abs - WND > 0) ? (t_abs - WND) : 0;
      int tmp = t_abs + WND + 1; if (tmp > T_) tmp = T_;
      int wl = tmp - left;
      float rf = rowfac_s[r];
      f32x4 o = {0.f, 0.f, 0.f, 0.f};
      int jj0 = c0 - left;
      if (jj0 > -4 && jj0 < wl) {
#pragma unroll
        for (int e = 0; e < 4; ++e) {
          int jj = jj0 + e;
          if (jj >= 0 && jj < wl) o[e] = Sf[r][r + jj] * rf;
        }
      }
      if (gm) {
        unsigned mm = gm;
        while (mm) {
          int g = __ffs(mm) - 1; mm &= mm - 1;
          o[gidx_s[g] - c0] += Sf[r][96 + g] * rf;
        }
      }
      float* dst = fa + (((size_t)(b * H_ + h) * T_) + t_abs) * T_ + c0;
      *(f32x4*)dst = o;
    }
  }
}

extern "C" void kernel_launch(void* const* d_in, const int* in_sizes, int n_in,
                              void* d_out, int out_size, void* d_ws, size_t ws_size,
                              hipStream_t stream) {
  const float* x   = (const float*)d_in[0];
  const int* gmask = (const int*)d_in[1];
  const float* wq  = (const float*)d_in[2];
  const float* wk  = (const float*)d_in[3];
  const float* wv  = (const float*)d_in[4];
  const float* wo  = (const float*)d_in[5];

  unsigned short* arena = (unsigned short*)d_ws;
  unsigned short* xb  = arena;                       // [2048][1024] bf16
  unsigned short* wqb = arena + 2 * 1048576;
  unsigned short* wkb = arena + 3 * 1048576;
  unsigned short* wvb = arena + 4 * 1048576;
  unsigned short* wob = arena + 5 * 1048576;
  unsigned short* qb   = arena + 6 * 1048576;        // [2048][1024] bf16
  unsigned short* kb   = arena + 8 * 1048576;
  unsigned short* vtb  = arena + 10 * 1048576;       // [b,h,d,t]
  unsigned short* ctxb = arena + 12 * 1048576;       // [2048][1024] bf16
  int*   gidx = (int*)(arena + 14 * 1048576);
  float* gval = (float*)(gidx + 64);

  float* outp = (float*)d_out;
  float* fa   = outp + 2097152;

  cvt_kernel<<<dim3(6145), dim3(256), 0, stream>>>(x, wq, wk, wv, wo, xb, gmask, gidx, gval);
  gemm128<0, 64, true><<<dim3(32, 8, 3), dim3(256), 0, stream>>>(xb, wqb, wkb, wvb, qb, kb, vtb);
  attn_kernel<<<dim3(32, 16, 2), dim3(512), 0, stream>>>(qb, kb, vtb, gidx, gval, ctxb, fa);
  gemm128<1, 64, false><<<dim3(32, 8, 1), dim3(256), 0, stream>>>(ctxb, wob, wob, wob, outp, outp, outp);
}

// Round 10
// 87.413 us; speedup vs baseline: 1.1071x; 1.0258x over previous
//
#include <hip/hip_runtime.h>

#define T_   1024
#define B_   2
#define H_   16
#define DH   64
#define D_   1024
#define WND  32
#define KSZ  65
#define NG   32

typedef float f32x4 __attribute__((ext_vector_type(4)));
typedef __bf16 bf16x8 __attribute__((ext_vector_type(8)));
typedef __bf16 bf16x4 __attribute__((ext_vector_type(4)));
typedef unsigned short u16x4 __attribute__((ext_vector_type(4)));

__device__ __forceinline__ unsigned short f2bf(float f) {
  unsigned u = __float_as_uint(f);
  return (unsigned short)((u + 0x7fffu + ((u >> 16) & 1u)) >> 16);
}

// async global->LDS 16B: linear LDS dest (wave-uniform base + lane*16).
__device__ __forceinline__ void gload16(const unsigned short* g, unsigned short* l) {
  __builtin_amdgcn_global_load_lds(
      (const __attribute__((address_space(1))) unsigned int*)g,
      (__attribute__((address_space(3))) unsigned int*)l, 16, 0, 0);
}

// ---------------- cvt x,Wq,Wk,Wv,Wo -> bf16 arena; side-block: gidx ballot scan ----------------
__global__ __launch_bounds__(256) void cvt_kernel(const float* __restrict__ x,
    const float* __restrict__ wq, const float* __restrict__ wk,
    const float* __restrict__ wv, const float* __restrict__ wo,
    unsigned short* __restrict__ dst,
    const int* __restrict__ mask, int* __restrict__ gidxo, float* __restrict__ gvalo) {
  if (blockIdx.x == 6144) {  // gidx side-block: stable argsort(!mask) first NG per batch
    if (threadIdx.x < 128) {
      int b = threadIdx.x >> 6, lane = threadIdx.x & 63;
      const int* mb = mask + b * T_;
      unsigned long long lanemask = (1ull << lane) - 1ull;
      int base = 0;
      for (int c = 0; c < 16 && base < NG; ++c) {
        int t = c * 64 + lane;
        bool m = mb[t] != 0;
        unsigned long long bal = __ballot(m);
        int rank = __popcll(bal & lanemask);
        if (m && base + rank < NG) { gidxo[b*NG+base+rank] = t; gvalo[b*NG+base+rank] = 1.f; }
        base += __popcll(bal);
      }
      if (base < NG) {
        for (int c = 0; c < 16 && base < NG; ++c) {
          int t = c * 64 + lane;
          bool m = mb[t] == 0;
          unsigned long long bal = __ballot(m);
          int rank = __popcll(bal & lanemask);
          if (m && base + rank < NG) { gidxo[b*NG+base+rank] = t; gvalo[b*NG+base+rank] = 0.f; }
          base += __popcll(bal);
        }
      }
    }
    return;
  }
  int idx = (blockIdx.x * 256 + threadIdx.x) * 4;
  int r = idx >> 20;
  const float* src; int off;
  if (r < 2)       { src = x;  off = idx; }
  else if (r == 2) { src = wq; off = idx - 2 * 1048576; }
  else if (r == 3) { src = wk; off = idx - 3 * 1048576; }
  else if (r == 4) { src = wv; off = idx - 4 * 1048576; }
  else             { src = wo; off = idx - 5 * 1048576; }
  f32x4 v = *(const f32x4*)(src + off);
  u16x4 o;
  o.x = f2bf(v[0]); o.y = f2bf(v[1]); o.z = f2bf(v[2]); o.w = f2bf(v[3]);
  *(u16x4*)(dst + idx) = o;
}

// ---------------- bf16 MFMA GEMM: C = A (MxK) * B^T (NxK), K=1024, BN=128 ----------------
// GLDS: global_load_lds staging (linear dest, pre-XOR source); else reg-staged.
// MODE 0: z in {0:Q,1:K} -> bf16 row-major [M][1024]; z==2: V -> bf16 [b,h,d,t] via transpose.
// MODE 1: C = f32 row-major [M][1024].
template<int MODE, int BM, int BK, bool GLDS>
__global__ __launch_bounds__(256) void gemm128(const unsigned short* __restrict__ A,
    const unsigned short* __restrict__ B0, const unsigned short* __restrict__ B1,
    const unsigned short* __restrict__ B2,
    void* __restrict__ C0v, void* __restrict__ C1v, void* __restrict__ C2v) {
  constexpr int K = 1024;
  constexpr int FM = BM / 32;
  constexpr int WM = BM / 2;
  constexpr int CPR = BK / 8;               // 16B chunks per row
  constexpr int AIT = BM * CPR / 256;       // A staging iters
  constexpr int BIT = 128 * CPR / 256;      // B staging iters
  __shared__ __attribute__((aligned(16))) unsigned short SMEM[BM * BK + 128 * BK];
  unsigned short* As = SMEM;
  unsigned short* Bs = SMEM + BM * BK;

  int m0 = blockIdx.x * BM, n0 = blockIdx.y * 128;
  int zz = (MODE == 0) ? blockIdx.z : 0;
  const unsigned short* Bb = (MODE == 0) ? (zz == 0 ? B0 : (zz == 1 ? B1 : B2)) : B0;

  int tid = threadIdx.x;
  int w = tid >> 6, l = tid & 63;
  int wr = w >> 1, wc = w & 1;
  int lr = l & 15, kg = l >> 4;

  f32x4 acc[FM][4] = {};

  for (int kt = 0; kt < K; kt += BK) {
    __syncthreads();
    if constexpr (GLDS) {
#pragma unroll
      for (int i = 0; i < AIT; ++i) {
        int ci = tid + 256 * i;
        int row = ci / CPR, c8 = (ci % CPR) ^ (row & 7);
        gload16(A + (size_t)(m0 + row) * K + kt + c8 * 8, As + ci * 8);
      }
#pragma unroll
      for (int i = 0; i < BIT; ++i) {
        int ci = tid + 256 * i;
        int row = ci / CPR, c8 = (ci % CPR) ^ (row & 7);
        gload16(Bb + (size_t)(n0 + row) * K + kt + c8 * 8, Bs + ci * 8);
      }
    } else {
#pragma unroll
      for (int i = 0; i < AIT; ++i) {
        int ci = tid + 256 * i;
        int row = ci / CPR, c8 = ci % CPR;
        *(bf16x8*)&As[row * BK + ((c8 ^ (row & 7)) * 8)] =
            *(const bf16x8*)&A[(size_t)(m0 + row) * K + kt + c8 * 8];
      }
#pragma unroll
      for (int i = 0; i < BIT; ++i) {
        int ci = tid + 256 * i;
        int row = ci / CPR, c8 = ci % CPR;
        *(bf16x8*)&Bs[row * BK + ((c8 ^ (row & 7)) * 8)] =
            *(const bf16x8*)&Bb[(size_t)(n0 + row) * K + kt + c8 * 8];
      }
    }
    __syncthreads();
#pragma unroll
    for (int kk = 0; kk < BK / 32; ++kk) {
      int c8 = kk * 4 + kg;
      bf16x8 af[FM], bfr[4];
#pragma unroll
      for (int mi = 0; mi < FM; ++mi) {
        int row = wr * WM + mi * 16 + lr;
        af[mi] = *(bf16x8*)&As[row * BK + (((c8 ^ (row & 7))) * 8)];
      }
#pragma unroll
      for (int ni = 0; ni < 4; ++ni) {
        int row = wc * 64 + ni * 16 + lr;
        bfr[ni] = *(bf16x8*)&Bs[row * BK + (((c8 ^ (row & 7))) * 8)];
      }
#pragma unroll
      for (int mi = 0; mi < FM; ++mi)
#pragma unroll
        for (int ni = 0; ni < 4; ++ni)
          acc[mi][ni] = __builtin_amdgcn_mfma_f32_16x16x32_bf16(af[mi], bfr[ni], acc[mi][ni], 0, 0, 0);
    }
  }

  if (MODE == 1) {
    float* C = (float*)C0v;
#pragma unroll
    for (int mi = 0; mi < FM; ++mi)
#pragma unroll
      for (int ni = 0; ni < 4; ++ni) {
        int mbase = m0 + wr * WM + mi * 16 + (l >> 4) * 4;
        int n = n0 + wc * 64 + ni * 16 + lr;
#pragma unroll
        for (int r = 0; r < 4; ++r)
          C[(size_t)(mbase + r) * 1024 + n] = acc[mi][ni][r];
      }
  } else if (zz < 2) {
    unsigned short* C = (unsigned short*)(zz == 0 ? C0v : C1v);
#pragma unroll
    for (int mi = 0; mi < FM; ++mi)
#pragma unroll
      for (int ni = 0; ni < 4; ++ni) {
        int mbase = m0 + wr * WM + mi * 16 + (l >> 4) * 4;
        int n = n0 + wc * 64 + ni * 16 + lr;
#pragma unroll
        for (int r = 0; r < 4; ++r) {
          __bf16 v = (__bf16)acc[mi][ni][r];
          C[(size_t)(mbase + r) * 1024 + n] = *(unsigned short*)&v;
        }
      }
  } else {
    // V: compact LDS transpose [128][BM] (swizzled) -> coalesced [b,h,d,t] stores
    constexpr int RS = BM * 2;            // row stride bytes
    constexpr int TCH = BM / 8;           // bf16x8 chunks per row
    constexpr int NIT = 128 * TCH / 256;
    __syncthreads();
    char* Tb = (char*)SMEM;
#pragma unroll
    for (int mi = 0; mi < FM; ++mi)
#pragma unroll
      for (int ni = 0; ni < 4; ++ni) {
        int mb2 = wr * WM + mi * 16 + (l >> 4) * 4;
        int nl = wc * 64 + ni * 16 + lr;
        bf16x4 pk;
        pk[0] = (__bf16)acc[mi][ni][0]; pk[1] = (__bf16)acc[mi][ni][1];
        pk[2] = (__bf16)acc[mi][ni][2]; pk[3] = (__bf16)acc[mi][ni][3];
        *(bf16x4*)(Tb + ((nl * RS + mb2 * 2) ^ ((nl & 7) << 4))) = pk;
      }
    __syncthreads();
    unsigned short* C = (unsigned short*)C2v;
    int bb = m0 >> 10, tbase = m0 & 1023;
#pragma unroll
    for (int it = 0; it < NIT; ++it) {
      int ci = tid + 256 * it;
      int dl = ci / TCH, tc = ci % TCH;
      bf16x8 v = *(bf16x8*)(Tb + ((dl * RS + tc * 16) ^ ((dl & 7) << 4)));
      int n = n0 + dl, hh = n >> 6, dd = n & 63;
      *(bf16x8*)&C[((size_t)(bb * H_ + hh) * DH + dd) * T_ + tbase + tc * 8] = v;
    }
  }
}

// ---------------- attention core: MFMA scores + MFMA PV, dual softmax, fused fa ----------------
// q,k: bf16 row-major [b*T][1024] (col = h*64+d). v: bf16 [b,h,d,t].
// XCD-aware swizzle: 1024 blocks, 8 XCDs -> 128 consecutive work-units per XCD
// (consecutive t0 within same (b,h) share 2/3 of their K/V window -> L2 hits).
__global__ __launch_bounds__(512, 4) void attn_kernel(
    const unsigned short* __restrict__ qg, const unsigned short* __restrict__ kg_,
    const unsigned short* __restrict__ vg,
    const int* __restrict__ gidx_g, const float* __restrict__ gval_g,
    unsigned short* __restrict__ ctxb, float* __restrict__ fa) {
  int tid = threadIdx.x;
  int lid = blockIdx.x + 32 * blockIdx.y + 512 * blockIdx.z;
  int swz = (lid & 7) * 128 + (lid >> 3);          // bijective: 1024 % 8 == 0
  int b = swz >> 9, h = (swz >> 5) & 15;
  int t0 = (swz & 31) * 32;
  int lane = tid & 63, wv = tid >> 6;

  __shared__ __attribute__((aligned(16))) unsigned short QbL[32 * 64];
  __shared__ __attribute__((aligned(16))) unsigned short KbL[128 * 64];
  __shared__ __attribute__((aligned(16))) unsigned short VtL[64 * 128];
  __shared__ __attribute__((aligned(16))) unsigned short WbL[32 * 128];
  __shared__ __attribute__((aligned(16))) float Sf[32][132];
  __shared__ float m_out_s[32], invdo_s[32], rowfac_s[32];
  __shared__ int   gidx_s[32];
  __shared__ float gval_s[32];

  if (tid < 32) { gidx_s[tid] = gidx_g[b * NG + tid]; gval_s[tid] = gval_g[b * NG + tid]; }
  ((unsigned long long*)WbL)[tid] = 0ull;
  ((unsigned long long*)WbL)[tid + 512] = 0ull;
  __syncthreads();

  const unsigned short* qbh = qg + (size_t)(b * T_ + t0) * D_ + h * DH;
  const unsigned short* kbh = kg_ + (size_t)(b * T_) * D_ + h * DH;
  const unsigned short* vbh = vg + (size_t)(b * H_ + h) * DH * T_;

  if (tid < 256) {
    int r = tid >> 3, c8 = tid & 7;
    bf16x8 v = *(const bf16x8*)(qbh + (size_t)r * D_ + c8 * 8);
    *(bf16x8*)((char*)QbL + ((r * 128 + c8 * 16) ^ ((r & 7) << 4))) = v;
  }
#pragma unroll
  for (int it = 0; it < 2; ++it) {
    int fi = tid + it * 512;
    int r = fi >> 3, c8 = fi & 7;
    int col; bool valid;
    if (r < 96) { col = t0 - 32 + r; valid = (col >= 0 && col < T_); }
    else { int g = r - 96; valid = gval_s[g] > 0.f; col = valid ? gidx_s[g] : 0; }
    bf16x8 v = {};
    if (valid) v = *(const bf16x8*)(kbh + (size_t)col * D_ + c8 * 8);
    *(bf16x8*)((char*)KbL + ((r * 128 + c8 * 16) ^ ((r & 7) << 4))) = v;
  }
#pragma unroll
  for (int it = 0; it < 2; ++it) {
    int fi = tid + it * 512;
    if (fi < 768) {
      int d = fi / 12, rc = fi % 12;
      int cb = t0 - 32 + rc * 8;
      bf16x8 v = {};
      if (cb >= 0 && cb < T_) v = *(const bf16x8*)(vbh + d * T_ + cb);
      *(bf16x8*)((char*)VtL + ((d * 256 + rc * 16) ^ ((d & 7) << 4))) = v;
    }
  }
#pragma unroll
  for (int it = 0; it < 4; ++it) {
    int fi = tid + it * 512;
    int d = fi >> 5, g = fi & 31;
    unsigned short v = 0;
    if (gval_s[g] > 0.f) v = vbh[d * T_ + gidx_s[g]];
    *(unsigned short*)((char*)VtL + ((d * 256 + (96 + g) * 2) ^ ((d & 7) << 4))) = v;
  }
  __syncthreads();

  // phase 1: S = Q·K^T via MFMA
  {
    int mt = wv & 1, nq = wv >> 1;
    int lrr = lane & 15, kgl = lane >> 4;
    int arow = mt * 16 + lrr;
    f32x4 acc0 = {}, acc1 = {};
#pragma unroll
    for (int s = 0; s < 2; ++s) {
      int c = s * 4 + kgl;
      bf16x8 a = *(bf16x8*)((char*)QbL + ((arow * 128 + c * 16) ^ ((arow & 7) << 4)));
      int br0 = nq * 32 + lrr, br1 = nq * 32 + 16 + lrr;
      bf16x8 b0 = *(bf16x8*)((char*)KbL + ((br0 * 128 + c * 16) ^ ((br0 & 7) << 4)));
      bf16x8 b1 = *(bf16x8*)((char*)KbL + ((br1 * 128 + c * 16) ^ ((br1 & 7) << 4)));
      acc0 = __builtin_amdgcn_mfma_f32_16x16x32_bf16(a, b0, acc0, 0, 0, 0);
      acc1 = __builtin_amdgcn_mfma_f32_16x16x32_bf16(a, b1, acc1, 0, 0, 0);
    }
    int orow = mt * 16 + (lane >> 4) * 4;
#pragma unroll
    for (int i = 0; i < 4; ++i) {
      Sf[orow + i][nq * 32 + lrr] = acc0[i] * 0.125f;
      Sf[orow + i][nq * 32 + 16 + lrr] = acc1[i] * 0.125f;
    }
  }
  __syncthreads();

  // phase 2: per-row stats for both softmaxes
  {
    int r = tid >> 4, lg = tid & 15;
    int t_abs = t0 + r;
    int left = (t_abs - WND > 0) ? (t_abs - WND) : 0;
    int tmp = t_abs + WND + 1; if (tmp > T_) tmp = T_;
    int wl = tmp - left;
    float sv[8]; bool vld[8], vdd[8];
#pragma unroll
    for (int ii = 0; ii < 8; ++ii) {
      int c = lg + ii * 16;
      bool loc = (c >= r && c <= r + 64);
      bool glob = (c >= 96);
      float s = Sf[r][c];
      if (glob && !(gval_s[c - 96] > 0.f)) s = -1e9f;
      vld[ii] = loc || glob;
      vdd[ii] = loc ? ((c - r) < wl) : glob;
      sv[ii] = s;
    }
    float mo = -1e30f, md = -1e30f;
#pragma unroll
    for (int ii = 0; ii < 8; ++ii) {
      if (vld[ii]) mo = fmaxf(mo, sv[ii]);
      if (vdd[ii]) md = fmaxf(md, sv[ii]);
    }
#pragma unroll
    for (int o = 1; o < 16; o <<= 1) {
      mo = fmaxf(mo, __shfl_xor(mo, o, 16));
      md = fmaxf(md, __shfl_xor(md, o, 16));
    }
    float eo = 0.f, ed = 0.f;
#pragma unroll
    for (int ii = 0; ii < 8; ++ii) {
      if (vld[ii]) eo += __expf(sv[ii] - mo);
      if (vdd[ii]) ed += __expf(sv[ii] - md);
    }
#pragma unroll
    for (int o = 1; o < 16; o <<= 1) {
      eo += __shfl_xor(eo, o, 16);
      ed += __shfl_xor(ed, o, 16);
    }
    if (lg == 0) {
      m_out_s[r] = mo;
      invdo_s[r] = 1.f / eo;
      rowfac_s[r] = (eo / ed) * __expf(mo - md);
    }
  }
  __syncthreads();

  // phase 2b: scores -> out-path weights (f32 in Sf, bf16 in Wb)
  for (int idx = tid; idx < 32 * 97; idx += 512) {
    int t = idx / 97;
    int j = idx - t * 97;
    int cc = (j < KSZ) ? (t + j) : (j + 31);
    float s = Sf[t][cc];
    float wgt = __expf(s - m_out_s[t]) * invdo_s[t];
    Sf[t][cc] = wgt;
    *(unsigned short*)((char*)WbL + ((t * 256 + cc * 2) ^ ((t & 7) << 4))) = f2bf(wgt);
  }
  __syncthreads();

  // phase 3: ctx^T = V^T · W^T via MFMA
  {
    int mt = wv >> 1, nt = wv & 1;
    int lrr = lane & 15, kgl = lane >> 4;
    int arow = mt * 16 + lrr;
    int brow = nt * 16 + lrr;
    f32x4 acc = {};
#pragma unroll
    for (int s = 0; s < 4; ++s) {
      int c = s * 4 + kgl;
      bf16x8 a = *(bf16x8*)((char*)VtL + ((arow * 256 + c * 16) ^ ((arow & 7) << 4)));
      bf16x8 bb = *(bf16x8*)((char*)WbL + ((brow * 256 + c * 16) ^ ((brow & 7) << 4)));
      acc = __builtin_amdgcn_mfma_f32_16x16x32_bf16(a, bb, acc, 0, 0, 0);
    }
    int t = nt * 16 + lrr;
    int dbase = mt * 16 + (lane >> 4) * 4;
    u16x4 st;
    st.x = f2bf(acc[0]); st.y = f2bf(acc[1]); st.z = f2bf(acc[2]); st.w = f2bf(acc[3]);
    *(u16x4*)(ctxb + ((size_t)(b * T_ + t0 + t)) * D_ + h * DH + dbase) = st;
  }

  // phase 4: dense full_attn rows
  {
    int rp = tid >> 8;
    int c0 = (tid & 255) * 4;
    unsigned gm = 0;
#pragma unroll
    for (int g = 0; g < NG; ++g) {
      int gc = gidx_s[g];
      if (gval_s[g] > 0.f && gc >= c0 && gc < c0 + 4) gm |= (1u << g);
    }
#pragma unroll 2
    for (int rr = 0; rr < 16; ++rr) {
      int r = rr * 2 + rp;
      int t_abs = t0 + r;
      int left = (t_abs - WND > 0) ? (t_abs - WND) : 0;
      int tmp = t_abs + WND + 1; if (tmp > T_) tmp = T_;
      int wl = tmp - left;
      float rf = rowfac_s[r];
      f32x4 o = {0.f, 0.f, 0.f, 0.f};
      int jj0 = c0 - left;
      if (jj0 > -4 && jj0 < wl) {
#pragma unroll
        for (int e = 0; e < 4; ++e) {
          int jj = jj0 + e;
          if (jj >= 0 && jj < wl) o[e] = Sf[r][r + jj] * rf;
        }
      }
      if (gm) {
        unsigned mm = gm;
        while (mm) {
          int g = __ffs(mm) - 1; mm &= mm - 1;
          o[gidx_s[g] - c0] += Sf[r][96 + g] * rf;
        }
      }
      float* dst = fa + (((size_t)(b * H_ + h) * T_) + t_abs) * T_ + c0;
      *(f32x4*)dst = o;
    }
  }
}

extern "C" void kernel_launch(void* const* d_in, const int* in_sizes, int n_in,
                              void* d_out, int out_size, void* d_ws, size_t ws_size,
                              hipStream_t stream) {
  const float* x   = (const float*)d_in[0];
  const int* gmask = (const int*)d_in[1];
  const float* wq  = (const float*)d_in[2];
  const float* wk  = (const float*)d_in[3];
  const float* wv  = (const float*)d_in[4];
  const float* wo  = (const float*)d_in[5];

  unsigned short* arena = (unsigned short*)d_ws;
  unsigned short* xb  = arena;                       // [2048][1024] bf16
  unsigned short* wqb = arena + 2 * 1048576;
  unsigned short* wkb = arena + 3 * 1048576;
  unsigned short* wvb = arena + 4 * 1048576;
  unsigned short* wob = arena + 5 * 1048576;
  unsigned short* qb   = arena + 6 * 1048576;        // [2048][1024] bf16
  unsigned short* kb   = arena + 8 * 1048576;
  unsigned short* vtb  = arena + 10 * 1048576;       // [b,h,d,t]
  unsigned short* ctxb = arena + 12 * 1048576;       // [2048][1024] bf16
  int*   gidx = (int*)(arena + 14 * 1048576);
  float* gval = (float*)(gidx + 64);

  float* outp = (float*)d_out;
  float* fa   = outp + 2097152;

  cvt_kernel<<<dim3(6145), dim3(256), 0, stream>>>(x, wq, wk, wv, wo, xb, gmask, gidx, gval);
  gemm128<0, 64, 128, true><<<dim3(32, 8, 3), dim3(256), 0, stream>>>(xb, wqb, wkb, wvb, qb, kb, vtb);
  attn_kernel<<<dim3(32, 16, 2), dim3(512), 0, stream>>>(qb, kb, vtb, gidx, gval, ctxb, fa);
  gemm128<1, 64, 64, false><<<dim3(32, 8, 1), dim3(256), 0, stream>>>(ctxb, wob, wob, wob, outp, outp, outp);
}

// Round 11
// 86.704 us; speedup vs baseline: 1.1161x; 1.0082x over previous
//
#include <hip/hip_runtime.h>

#define T_   1024
#define B_   2
#define H_   16
#define DH   64
#define D_   1024
#define WND  32
#define KSZ  65
#define NG   32

typedef float f32x4 __attribute__((ext_vector_type(4)));
typedef __bf16 bf16x8 __attribute__((ext_vector_type(8)));
typedef __bf16 bf16x4 __attribute__((ext_vector_type(4)));
typedef unsigned short u16x4 __attribute__((ext_vector_type(4)));

__device__ __forceinline__ unsigned short f2bf(float f) {
  unsigned u = __float_as_uint(f);
  return (unsigned short)((u + 0x7fffu + ((u >> 16) & 1u)) >> 16);
}

// async global->LDS 16B: linear LDS dest (wave-uniform base + lane*16).
__device__ __forceinline__ void gload16(const unsigned short* g, unsigned short* l) {
  __builtin_amdgcn_global_load_lds(
      (const __attribute__((address_space(1))) unsigned int*)g,
      (__attribute__((address_space(3))) unsigned int*)l, 16, 0, 0);
}

// Sf overlay index: [32][128] f32 with XOR bank-spread
#define SFIDX(r, c) ((r) * 128 + ((c) ^ (((r) & 7) << 3)))

// ---------------- cvt x,Wq,Wk,Wv,Wo -> bf16 arena; side-block: gidx ballot scan ----------------
__global__ __launch_bounds__(256) void cvt_kernel(const float* __restrict__ x,
    const float* __restrict__ wq, const float* __restrict__ wk,
    const float* __restrict__ wv, const float* __restrict__ wo,
    unsigned short* __restrict__ dst,
    const int* __restrict__ mask, int* __restrict__ gidxo, float* __restrict__ gvalo) {
  if (blockIdx.x == 6144) {  // gidx side-block: stable argsort(!mask) first NG per batch
    if (threadIdx.x < 128) {
      int b = threadIdx.x >> 6, lane = threadIdx.x & 63;
      const int* mb = mask + b * T_;
      unsigned long long lanemask = (1ull << lane) - 1ull;
      int base = 0;
      for (int c = 0; c < 16 && base < NG; ++c) {
        int t = c * 64 + lane;
        bool m = mb[t] != 0;
        unsigned long long bal = __ballot(m);
        int rank = __popcll(bal & lanemask);
        if (m && base + rank < NG) { gidxo[b*NG+base+rank] = t; gvalo[b*NG+base+rank] = 1.f; }
        base += __popcll(bal);
      }
      if (base < NG) {
        for (int c = 0; c < 16 && base < NG; ++c) {
          int t = c * 64 + lane;
          bool m = mb[t] == 0;
          unsigned long long bal = __ballot(m);
          int rank = __popcll(bal & lanemask);
          if (m && base + rank < NG) { gidxo[b*NG+base+rank] = t; gvalo[b*NG+base+rank] = 0.f; }
          base += __popcll(bal);
        }
      }
    }
    return;
  }
  int idx = (blockIdx.x * 256 + threadIdx.x) * 4;
  int r = idx >> 20;
  const float* src; int off;
  if (r < 2)       { src = x;  off = idx; }
  else if (r == 2) { src = wq; off = idx - 2 * 1048576; }
  else if (r == 3) { src = wk; off = idx - 3 * 1048576; }
  else if (r == 4) { src = wv; off = idx - 4 * 1048576; }
  else             { src = wo; off = idx - 5 * 1048576; }
  f32x4 v = *(const f32x4*)(src + off);
  u16x4 o;
  o.x = f2bf(v[0]); o.y = f2bf(v[1]); o.z = f2bf(v[2]); o.w = f2bf(v[3]);
  *(u16x4*)(dst + idx) = o;
}

// ---------------- bf16 MFMA GEMM (QKV): C = A (MxK) * B^T (NxK), K=1024, BN=128 ----------------
// gload_lds staging (linear dest, pre-XOR source). z in {0:Q,1:K} -> bf16 row-major [M][1024];
// z==2: V -> bf16 [b,h,d,t] via compact LDS-transpose epilogue.
template<int BM, int BK>
__global__ __launch_bounds__(256) void gemm128(const unsigned short* __restrict__ A,
    const unsigned short* __restrict__ B0, const unsigned short* __restrict__ B1,
    const unsigned short* __restrict__ B2,
    void* __restrict__ C0v, void* __restrict__ C1v, void* __restrict__ C2v) {
  constexpr int K = 1024;
  constexpr int FM = BM / 32;
  constexpr int WM = BM / 2;
  constexpr int CPR = BK / 8;
  constexpr int AIT = BM * CPR / 256;
  constexpr int BIT = 128 * CPR / 256;
  __shared__ __attribute__((aligned(16))) unsigned short SMEM[BM * BK + 128 * BK];
  unsigned short* As = SMEM;
  unsigned short* Bs = SMEM + BM * BK;

  int m0 = blockIdx.x * BM, n0 = blockIdx.y * 128;
  int zz = blockIdx.z;
  const unsigned short* Bb = (zz == 0 ? B0 : (zz == 1 ? B1 : B2));

  int tid = threadIdx.x;
  int w = tid >> 6, l = tid & 63;
  int wr = w >> 1, wc = w & 1;
  int lr = l & 15, kg = l >> 4;

  f32x4 acc[FM][4] = {};

  for (int kt = 0; kt < K; kt += BK) {
    __syncthreads();
#pragma unroll
    for (int i = 0; i < AIT; ++i) {
      int ci = tid + 256 * i;
      int row = ci / CPR, c8 = (ci % CPR) ^ (row & 7);
      gload16(A + (size_t)(m0 + row) * K + kt + c8 * 8, As + ci * 8);
    }
#pragma unroll
    for (int i = 0; i < BIT; ++i) {
      int ci = tid + 256 * i;
      int row = ci / CPR, c8 = (ci % CPR) ^ (row & 7);
      gload16(Bb + (size_t)(n0 + row) * K + kt + c8 * 8, Bs + ci * 8);
    }
    __syncthreads();
#pragma unroll
    for (int kk = 0; kk < BK / 32; ++kk) {
      int c8 = kk * 4 + kg;
      bf16x8 af[FM], bfr[4];
#pragma unroll
      for (int mi = 0; mi < FM; ++mi) {
        int row = wr * WM + mi * 16 + lr;
        af[mi] = *(bf16x8*)&As[row * BK + (((c8 ^ (row & 7))) * 8)];
      }
#pragma unroll
      for (int ni = 0; ni < 4; ++ni) {
        int row = wc * 64 + ni * 16 + lr;
        bfr[ni] = *(bf16x8*)&Bs[row * BK + (((c8 ^ (row & 7))) * 8)];
      }
#pragma unroll
      for (int mi = 0; mi < FM; ++mi)
#pragma unroll
        for (int ni = 0; ni < 4; ++ni)
          acc[mi][ni] = __builtin_amdgcn_mfma_f32_16x16x32_bf16(af[mi], bfr[ni], acc[mi][ni], 0, 0, 0);
    }
  }

  if (zz < 2) {
    unsigned short* C = (unsigned short*)(zz == 0 ? C0v : C1v);
#pragma unroll
    for (int mi = 0; mi < FM; ++mi)
#pragma unroll
      for (int ni = 0; ni < 4; ++ni) {
        int mbase = m0 + wr * WM + mi * 16 + (l >> 4) * 4;
        int n = n0 + wc * 64 + ni * 16 + lr;
#pragma unroll
        for (int r = 0; r < 4; ++r) {
          __bf16 v = (__bf16)acc[mi][ni][r];
          C[(size_t)(mbase + r) * 1024 + n] = *(unsigned short*)&v;
        }
      }
  } else {
    // V: compact LDS transpose [128][BM] (swizzled) -> coalesced [b,h,d,t] stores
    constexpr int RS = BM * 2;
    constexpr int TCH = BM / 8;
    constexpr int NIT = 128 * TCH / 256;
    __syncthreads();
    char* Tb = (char*)SMEM;
#pragma unroll
    for (int mi = 0; mi < FM; ++mi)
#pragma unroll
      for (int ni = 0; ni < 4; ++ni) {
        int mb2 = wr * WM + mi * 16 + (l >> 4) * 4;
        int nl = wc * 64 + ni * 16 + lr;
        bf16x4 pk;
        pk[0] = (__bf16)acc[mi][ni][0]; pk[1] = (__bf16)acc[mi][ni][1];
        pk[2] = (__bf16)acc[mi][ni][2]; pk[3] = (__bf16)acc[mi][ni][3];
        *(bf16x4*)(Tb + ((nl * RS + mb2 * 2) ^ ((nl & 7) << 4))) = pk;
      }
    __syncthreads();
    unsigned short* C = (unsigned short*)C2v;
    int bb = m0 >> 10, tbase = m0 & 1023;
#pragma unroll
    for (int it = 0; it < NIT; ++it) {
      int ci = tid + 256 * it;
      int dl = ci / TCH, tc = ci % TCH;
      bf16x8 v = *(bf16x8*)(Tb + ((dl * RS + tc * 16) ^ ((dl & 7) << 4)));
      int n = n0 + dl, hh = n >> 6, dd = n & 63;
      *(bf16x8*)&C[((size_t)(bb * H_ + hh) * DH + dd) * T_ + tbase + tc * 8] = v;
    }
  }
}

// ---------------- out GEMM: C(f32) = ctx(bf16) * Wo^T. BM=64, BN=64 -> 512 blocks ----------------
__global__ __launch_bounds__(256) void out_gemm(const unsigned short* __restrict__ A,
    const unsigned short* __restrict__ Bw, float* __restrict__ C) {
  constexpr int K = 1024;
  __shared__ __attribute__((aligned(16))) unsigned short SMEM[64 * 64 * 2];
  unsigned short* As = SMEM;
  unsigned short* Bs = SMEM + 64 * 64;

  int m0 = blockIdx.x * 64, n0 = blockIdx.y * 64;
  int tid = threadIdx.x;
  int w = tid >> 6, l = tid & 63;
  int wr = w >> 1, wc = w & 1;
  int lr = l & 15, kg = l >> 4;

  f32x4 acc[2][2] = {};

  for (int kt = 0; kt < K; kt += 64) {
    __syncthreads();
#pragma unroll
    for (int i = 0; i < 2; ++i) {
      int ci = tid + 256 * i;
      int row = ci >> 3, c8 = (ci & 7) ^ (row & 7);
      gload16(A + (size_t)(m0 + row) * K + kt + c8 * 8, As + ci * 8);
    }
#pragma unroll
    for (int i = 0; i < 2; ++i) {
      int ci = tid + 256 * i;
      int row = ci >> 3, c8 = (ci & 7) ^ (row & 7);
      gload16(Bw + (size_t)(n0 + row) * K + kt + c8 * 8, Bs + ci * 8);
    }
    __syncthreads();
#pragma unroll
    for (int kk = 0; kk < 2; ++kk) {
      int c8 = kk * 4 + kg;
      bf16x8 af[2], bfr[2];
#pragma unroll
      for (int mi = 0; mi < 2; ++mi) {
        int row = wr * 32 + mi * 16 + lr;
        af[mi] = *(bf16x8*)&As[row * 64 + ((c8 ^ (row & 7)) * 8)];
      }
#pragma unroll
      for (int ni = 0; ni < 2; ++ni) {
        int row = wc * 32 + ni * 16 + lr;
        bfr[ni] = *(bf16x8*)&Bs[row * 64 + ((c8 ^ (row & 7)) * 8)];
      }
#pragma unroll
      for (int mi = 0; mi < 2; ++mi)
#pragma unroll
        for (int ni = 0; ni < 2; ++ni)
          acc[mi][ni] = __builtin_amdgcn_mfma_f32_16x16x32_bf16(af[mi], bfr[ni], acc[mi][ni], 0, 0, 0);
    }
  }

#pragma unroll
  for (int mi = 0; mi < 2; ++mi)
#pragma unroll
    for (int ni = 0; ni < 2; ++ni) {
      int mbase = m0 + wr * 32 + mi * 16 + (l >> 4) * 4;
      int n = n0 + wc * 32 + ni * 16 + lr;
#pragma unroll
      for (int r = 0; r < 4; ++r)
        C[(size_t)(mbase + r) * 1024 + n] = acc[mi][ni][r];
    }
}

// ---------------- attention core: MFMA scores + MFMA PV, dual softmax, fused fa ----------------
// q,k: bf16 row-major [b*T][1024] (col = h*64+d). v: bf16 [b,h,d,t].
// Sf overlaid on KbL (dead after phase 1) -> 44.6 KB LDS -> 3 blocks/CU.
__global__ __launch_bounds__(512, 6) void attn_kernel(
    const unsigned short* __restrict__ qg, const unsigned short* __restrict__ kg_,
    const unsigned short* __restrict__ vg,
    const int* __restrict__ gidx_g, const float* __restrict__ gval_g,
    unsigned short* __restrict__ ctxb, float* __restrict__ fa) {
  int tid = threadIdx.x;
  int lid = blockIdx.x + 32 * blockIdx.y + 512 * blockIdx.z;
  int swz = (lid & 7) * 128 + (lid >> 3);          // bijective: 1024 % 8 == 0
  int b = swz >> 9, h = (swz >> 5) & 15;
  int t0 = (swz & 31) * 32;
  int lane = tid & 63, wv = tid >> 6;

  __shared__ __attribute__((aligned(16))) unsigned short QbL[32 * 64];
  __shared__ __attribute__((aligned(16))) unsigned short KbL[128 * 64];   // phase<=1: K tile; after: Sf f32[32][128]
  __shared__ __attribute__((aligned(16))) unsigned short VtL[64 * 128];
  __shared__ __attribute__((aligned(16))) unsigned short WbL[32 * 128];
  __shared__ float m_out_s[32], invdo_s[32], rowfac_s[32];
  __shared__ int   gidx_s[32];
  __shared__ float gval_s[32];
  float* Sfp = (float*)KbL;

  if (tid < 32) { gidx_s[tid] = gidx_g[b * NG + tid]; gval_s[tid] = gval_g[b * NG + tid]; }
  ((unsigned long long*)WbL)[tid] = 0ull;
  ((unsigned long long*)WbL)[tid + 512] = 0ull;
  __syncthreads();

  const unsigned short* qbh = qg + (size_t)(b * T_ + t0) * D_ + h * DH;
  const unsigned short* kbh = kg_ + (size_t)(b * T_) * D_ + h * DH;
  const unsigned short* vbh = vg + (size_t)(b * H_ + h) * DH * T_;

  if (tid < 256) {
    int r = tid >> 3, c8 = tid & 7;
    bf16x8 v = *(const bf16x8*)(qbh + (size_t)r * D_ + c8 * 8);
    *(bf16x8*)((char*)QbL + ((r * 128 + c8 * 16) ^ ((r & 7) << 4))) = v;
  }
#pragma unroll
  for (int it = 0; it < 2; ++it) {
    int fi = tid + it * 512;
    int r = fi >> 3, c8 = fi & 7;
    int col; bool valid;
    if (r < 96) { col = t0 - 32 + r; valid = (col >= 0 && col < T_); }
    else { int g = r - 96; valid = gval_s[g] > 0.f; col = valid ? gidx_s[g] : 0; }
    bf16x8 v = {};
    if (valid) v = *(const bf16x8*)(kbh + (size_t)col * D_ + c8 * 8);
    *(bf16x8*)((char*)KbL + ((r * 128 + c8 * 16) ^ ((r & 7) << 4))) = v;
  }
#pragma unroll
  for (int it = 0; it < 2; ++it) {
    int fi = tid + it * 512;
    if (fi < 768) {
      int d = fi / 12, rc = fi % 12;
      int cb = t0 - 32 + rc * 8;
      bf16x8 v = {};
      if (cb >= 0 && cb < T_) v = *(const bf16x8*)(vbh + d * T_ + cb);
      *(bf16x8*)((char*)VtL + ((d * 256 + rc * 16) ^ ((d & 7) << 4))) = v;
    }
  }
#pragma unroll
  for (int it = 0; it < 4; ++it) {
    int fi = tid + it * 512;
    int d = fi >> 5, g = fi & 31;
    unsigned short v = 0;
    if (gval_s[g] > 0.f) v = vbh[d * T_ + gidx_s[g]];
    *(unsigned short*)((char*)VtL + ((d * 256 + (96 + g) * 2) ^ ((d & 7) << 4))) = v;
  }
  __syncthreads();

  // phase 1: S = Q·K^T via MFMA (accs in regs; Sf written after barrier into KbL space)
  {
    int mt = wv & 1, nq = wv >> 1;
    int lrr = lane & 15, kgl = lane >> 4;
    int arow = mt * 16 + lrr;
    f32x4 acc0 = {}, acc1 = {};
#pragma unroll
    for (int s = 0; s < 2; ++s) {
      int c = s * 4 + kgl;
      bf16x8 a = *(bf16x8*)((char*)QbL + ((arow * 128 + c * 16) ^ ((arow & 7) << 4)));
      int br0 = nq * 32 + lrr, br1 = nq * 32 + 16 + lrr;
      bf16x8 b0 = *(bf16x8*)((char*)KbL + ((br0 * 128 + c * 16) ^ ((br0 & 7) << 4)));
      bf16x8 b1 = *(bf16x8*)((char*)KbL + ((br1 * 128 + c * 16) ^ ((br1 & 7) << 4)));
      acc0 = __builtin_amdgcn_mfma_f32_16x16x32_bf16(a, b0, acc0, 0, 0, 0);
      acc1 = __builtin_amdgcn_mfma_f32_16x16x32_bf16(a, b1, acc1, 0, 0, 0);
    }
    __syncthreads();  // all KbL reads done before Sf overlay writes
    int orow = mt * 16 + (lane >> 4) * 4;
#pragma unroll
    for (int i = 0; i < 4; ++i) {
      Sfp[SFIDX(orow + i, nq * 32 + lrr)] = acc0[i] * 0.125f;
      Sfp[SFIDX(orow + i, nq * 32 + 16 + lrr)] = acc1[i] * 0.125f;
    }
  }
  __syncthreads();

  // phase 2: per-row stats for both softmaxes
  {
    int r = tid >> 4, lg = tid & 15;
    int t_abs = t0 + r;
    int left = (t_abs - WND > 0) ? (t_abs - WND) : 0;
    int tmp = t_abs + WND + 1; if (tmp > T_) tmp = T_;
    int wl = tmp - left;
    float sv[8]; bool vld[8], vdd[8];
#pragma unroll
    for (int ii = 0; ii < 8; ++ii) {
      int c = lg + ii * 16;
      bool loc = (c >= r && c <= r + 64);
      bool glob = (c >= 96);
      float s = Sfp[SFIDX(r, c)];
      if (glob && !(gval_s[c - 96] > 0.f)) s = -1e9f;
      vld[ii] = loc || glob;
      vdd[ii] = loc ? ((c - r) < wl) : glob;
      sv[ii] = s;
    }
    float mo = -1e30f, md = -1e30f;
#pragma unroll
    for (int ii = 0; ii < 8; ++ii) {
      if (vld[ii]) mo = fmaxf(mo, sv[ii]);
      if (vdd[ii]) md = fmaxf(md, sv[ii]);
    }
#pragma unroll
    for (int o = 1; o < 16; o <<= 1) {
      mo = fmaxf(mo, __shfl_xor(mo, o, 16));
      md = fmaxf(md, __shfl_xor(md, o, 16));
    }
    float eo = 0.f, ed = 0.f;
#pragma unroll
    for (int ii = 0; ii < 8; ++ii) {
      if (vld[ii]) eo += __expf(sv[ii] - mo);
      if (vdd[ii]) ed += __expf(sv[ii] - md);
    }
#pragma unroll
    for (int o = 1; o < 16; o <<= 1) {
      eo += __shfl_xor(eo, o, 16);
      ed += __shfl_xor(ed, o, 16);
    }
    if (lg == 0) {
      m_out_s[r] = mo;
      invdo_s[r] = 1.f / eo;
      rowfac_s[r] = (eo / ed) * __expf(mo - md);
    }
  }
  __syncthreads();

  // phase 2b: scores -> out-path weights (f32 in Sf, bf16 in Wb)
  for (int idx = tid; idx < 32 * 97; idx += 512) {
    int t = idx / 97;
    int j = idx - t * 97;
    int cc = (j < KSZ) ? (t + j) : (j + 31);
    float s = Sfp[SFIDX(t, cc)];
    float wgt = __expf(s - m_out_s[t]) * invdo_s[t];
    Sfp[SFIDX(t, cc)] = wgt;
    *(unsigned short*)((char*)WbL + ((t * 256 + cc * 2) ^ ((t & 7) << 4))) = f2bf(wgt);
  }
  __syncthreads();

  // phase 3: ctx^T = V^T · W^T via MFMA
  {
    int mt = wv >> 1, nt = wv & 1;
    int lrr = lane & 15, kgl = lane >> 4;
    int arow = mt * 16 + lrr;
    int brow = nt * 16 + lrr;
    f32x4 acc = {};
#pragma unroll
    for (int s = 0; s < 4; ++s) {
      int c = s * 4 + kgl;
      bf16x8 a = *(bf16x8*)((char*)VtL + ((arow * 256 + c * 16) ^ ((arow & 7) << 4)));
      bf16x8 bb = *(bf16x8*)((char*)WbL + ((brow * 256 + c * 16) ^ ((brow & 7) << 4)));
      acc = __builtin_amdgcn_mfma_f32_16x16x32_bf16(a, bb, acc, 0, 0, 0);
    }
    int t = nt * 16 + lrr;
    int dbase = mt * 16 + (lane >> 4) * 4;
    u16x4 st;
    st.x = f2bf(acc[0]); st.y = f2bf(acc[1]); st.z = f2bf(acc[2]); st.w = f2bf(acc[3]);
    *(u16x4*)(ctxb + ((size_t)(b * T_ + t0 + t)) * D_ + h * DH + dbase) = st;
  }

  // phase 4: dense full_attn rows
  {
    int rp = tid >> 8;
    int c0 = (tid & 255) * 4;
    unsigned gm = 0;
#pragma unroll
    for (int g = 0; g < NG; ++g) {
      int gc = gidx_s[g];
      if (gval_s[g] > 0.f && gc >= c0 && gc < c0 + 4) gm |= (1u << g);
    }
#pragma unroll 2
    for (int rr = 0; rr < 16; ++rr) {
      int r = rr * 2 + rp;
      int t_abs = t0 + r;
      int left = (t_abs - WND > 0) ? (t_abs - WND) : 0;
      int tmp = t_abs + WND + 1; if (tmp > T_) tmp = T_;
      int wl = tmp - left;
      float rf = rowfac_s[r];
      f32x4 o = {0.f, 0.f, 0.f, 0.f};
      int jj0 = c0 - left;
      if (jj0 > -4 && jj0 < wl) {
#pragma unroll
        for (int e = 0; e < 4; ++e) {
          int jj = jj0 + e;
          if (jj >= 0 && jj < wl) o[e] = Sfp[SFIDX(r, r + jj)] * rf;
        }
      }
      if (gm) {
        unsigned mm = gm;
        while (mm) {
          int g = __ffs(mm) - 1; mm &= mm - 1;
          o[gidx_s[g] - c0] += Sfp[SFIDX(r, 96 + g)] * rf;
        }
      }
      float* dst = fa + (((size_t)(b * H_ + h) * T_) + t_abs) * T_ + c0;
      *(f32x4*)dst = o;
    }
  }
}

extern "C" void kernel_launch(void* const* d_in, const int* in_sizes, int n_in,
                              void* d_out, int out_size, void* d_ws, size_t ws_size,
                              hipStream_t stream) {
  const float* x   = (const float*)d_in[0];
  const int* gmask = (const int*)d_in[1];
  const float* wq  = (const float*)d_in[2];
  const float* wk  = (const float*)d_in[3];
  const float* wv  = (const float*)d_in[4];
  const float* wo  = (const float*)d_in[5];

  unsigned short* arena = (unsigned short*)d_ws;
  unsigned short* xb  = arena;                       // [2048][1024] bf16
  unsigned short* wqb = arena + 2 * 1048576;
  unsigned short* wkb = arena + 3 * 1048576;
  unsigned short* wvb = arena + 4 * 1048576;
  unsigned short* wob = arena + 5 * 1048576;
  unsigned short* qb   = arena + 6 * 1048576;        // [2048][1024] bf16
  unsigned short* kb   = arena + 8 * 1048576;
  unsigned short* vtb  = arena + 10 * 1048576;       // [b,h,d,t]
  unsigned short* ctxb = arena + 12 * 1048576;       // [2048][1024] bf16
  int*   gidx = (int*)(arena + 14 * 1048576);
  float* gval = (float*)(gidx + 64);

  float* outp = (float*)d_out;
  float* fa   = outp + 2097152;

  cvt_kernel<<<dim3(6145), dim3(256), 0, stream>>>(x, wq, wk, wv, wo, xb, gmask, gidx, gval);
  gemm128<64, 128><<<dim3(32, 8, 3), dim3(256), 0, stream>>>(xb, wqb, wkb, wvb, qb, kb, vtb);
  attn_kernel<<<dim3(32, 16, 2), dim3(512), 0, stream>>>(qb, kb, vtb, gidx, gval, ctxb, fa);
  out_gemm<<<dim3(32, 16), dim3(256), 0, stream>>>(ctxb, wob, outp);
}

// Round 12
// 80.898 us; speedup vs baseline: 1.1962x; 1.0718x over previous
//
#include <hip/hip_runtime.h>

#define T_   1024
#define B_   2
#define H_   16
#define DH   64
#define D_   1024
#define WND  32
#define KSZ  65
#define NG   32

typedef float f32x4 __attribute__((ext_vector_type(4)));
typedef __bf16 bf16x8 __attribute__((ext_vector_type(8)));
typedef __bf16 bf16x4 __attribute__((ext_vector_type(4)));
typedef unsigned short u16x4 __attribute__((ext_vector_type(4)));

__device__ __forceinline__ unsigned short f2bf(float f) {
  unsigned u = __float_as_uint(f);
  return (unsigned short)((u + 0x7fffu + ((u >> 16) & 1u)) >> 16);
}

// async global->LDS 16B: linear LDS dest (wave-uniform base + lane*16).
__device__ __forceinline__ void gload16(const unsigned short* g, unsigned short* l) {
  __builtin_amdgcn_global_load_lds(
      (const __attribute__((address_space(1))) unsigned int*)g,
      (__attribute__((address_space(3))) unsigned int*)l, 16, 0, 0);
}

// Sf overlay index: [32][128] f32 with XOR bank-spread
#define SFIDX(r, c) ((r) * 128 + ((c) ^ (((r) & 7) << 3)))

// ---------------- cvt x,Wq,Wk,Wv,Wo -> bf16 arena; side-block: gidx ballot scan ----------------
__global__ __launch_bounds__(256) void cvt_kernel(const float* __restrict__ x,
    const float* __restrict__ wq, const float* __restrict__ wk,
    const float* __restrict__ wv, const float* __restrict__ wo,
    unsigned short* __restrict__ dst,
    const int* __restrict__ mask, int* __restrict__ gidxo, float* __restrict__ gvalo) {
  if (blockIdx.x == 6144) {  // gidx side-block: stable argsort(!mask) first NG per batch
    if (threadIdx.x < 128) {
      int b = threadIdx.x >> 6, lane = threadIdx.x & 63;
      const int* mb = mask + b * T_;
      unsigned long long lanemask = (1ull << lane) - 1ull;
      int base = 0;
      for (int c = 0; c < 16 && base < NG; ++c) {
        int t = c * 64 + lane;
        bool m = mb[t] != 0;
        unsigned long long bal = __ballot(m);
        int rank = __popcll(bal & lanemask);
        if (m && base + rank < NG) { gidxo[b*NG+base+rank] = t; gvalo[b*NG+base+rank] = 1.f; }
        base += __popcll(bal);
      }
      if (base < NG) {
        for (int c = 0; c < 16 && base < NG; ++c) {
          int t = c * 64 + lane;
          bool m = mb[t] == 0;
          unsigned long long bal = __ballot(m);
          int rank = __popcll(bal & lanemask);
          if (m && base + rank < NG) { gidxo[b*NG+base+rank] = t; gvalo[b*NG+base+rank] = 0.f; }
          base += __popcll(bal);
        }
      }
    }
    return;
  }
  int idx = (blockIdx.x * 256 + threadIdx.x) * 4;
  int r = idx >> 20;
  const float* src; int off;
  if (r < 2)       { src = x;  off = idx; }
  else if (r == 2) { src = wq; off = idx - 2 * 1048576; }
  else if (r == 3) { src = wk; off = idx - 3 * 1048576; }
  else if (r == 4) { src = wv; off = idx - 4 * 1048576; }
  else             { src = wo; off = idx - 5 * 1048576; }
  f32x4 v = *(const f32x4*)(src + off);
  u16x4 o;
  o.x = f2bf(v[0]); o.y = f2bf(v[1]); o.z = f2bf(v[2]); o.w = f2bf(v[3]);
  *(u16x4*)(dst + idx) = o;
}

// ---------------- bf16 MFMA GEMM (QKV): 2-phase dbuf gload_lds, BN=128 ----------------
// STAGE(next) issued BEFORE compute(cur); one barrier per K-step (T3 minimum-2-phase).
// z in {0:Q,1:K} -> bf16 row-major [M][1024]; z==2: V -> [b,h,d,t] via LDS transpose.
template<int BM, int BK>
__global__ __launch_bounds__(256) void gemm128(const unsigned short* __restrict__ A,
    const unsigned short* __restrict__ B0, const unsigned short* __restrict__ B1,
    const unsigned short* __restrict__ B2,
    void* __restrict__ C0v, void* __restrict__ C1v, void* __restrict__ C2v) {
  constexpr int K = 1024;
  constexpr int FM = BM / 32;
  constexpr int WM = BM / 2;
  constexpr int CPR = BK / 8;
  constexpr int AIT = BM * CPR / 256;
  constexpr int BIT = 128 * CPR / 256;
  constexpr int HALF = (BM + 128) * BK;
  __shared__ __attribute__((aligned(16))) unsigned short SMEM[2 * HALF];

  int m0 = blockIdx.x * BM, n0 = blockIdx.y * 128;
  int zz = blockIdx.z;
  const unsigned short* Bb = (zz == 0 ? B0 : (zz == 1 ? B1 : B2));

  int tid = threadIdx.x;
  int w = tid >> 6, l = tid & 63;
  int wr = w >> 1, wc = w & 1;
  int lr = l & 15, kg = l >> 4;

  f32x4 acc[FM][4] = {};

  // prologue stage into buf0
  {
    unsigned short* As = SMEM;
    unsigned short* Bs = SMEM + BM * BK;
#pragma unroll
    for (int i = 0; i < AIT; ++i) {
      int ci = tid + 256 * i;
      int row = ci / CPR, c8 = (ci % CPR) ^ (row & 7);
      gload16(A + (size_t)(m0 + row) * K + c8 * 8, As + ci * 8);
    }
#pragma unroll
    for (int i = 0; i < BIT; ++i) {
      int ci = tid + 256 * i;
      int row = ci / CPR, c8 = (ci % CPR) ^ (row & 7);
      gload16(Bb + (size_t)(n0 + row) * K + c8 * 8, Bs + ci * 8);
    }
  }
  __syncthreads();

  int cur = 0;
  for (int kt = 0; kt < K; kt += BK) {
    // stage NEXT tile into the other buffer (loads fly under this iter's compute)
    if (kt + BK < K) {
      unsigned short* As = SMEM + (cur ^ 1) * HALF;
      unsigned short* Bs = As + BM * BK;
      int ktn = kt + BK;
#pragma unroll
      for (int i = 0; i < AIT; ++i) {
        int ci = tid + 256 * i;
        int row = ci / CPR, c8 = (ci % CPR) ^ (row & 7);
        gload16(A + (size_t)(m0 + row) * K + ktn + c8 * 8, As + ci * 8);
      }
#pragma unroll
      for (int i = 0; i < BIT; ++i) {
        int ci = tid + 256 * i;
        int row = ci / CPR, c8 = (ci % CPR) ^ (row & 7);
        gload16(Bb + (size_t)(n0 + row) * K + ktn + c8 * 8, Bs + ci * 8);
      }
    }
    // compute on cur
    {
      unsigned short* As = SMEM + cur * HALF;
      unsigned short* Bs = As + BM * BK;
#pragma unroll
      for (int kk = 0; kk < BK / 32; ++kk) {
        int c8 = kk * 4 + kg;
        bf16x8 af[FM], bfr[4];
#pragma unroll
        for (int mi = 0; mi < FM; ++mi) {
          int row = wr * WM + mi * 16 + lr;
          af[mi] = *(bf16x8*)&As[row * BK + ((c8 ^ (row & 7)) * 8)];
        }
#pragma unroll
        for (int ni = 0; ni < 4; ++ni) {
          int row = wc * 64 + ni * 16 + lr;
          bfr[ni] = *(bf16x8*)&Bs[row * BK + ((c8 ^ (row & 7)) * 8)];
        }
#pragma unroll
        for (int mi = 0; mi < FM; ++mi)
#pragma unroll
          for (int ni = 0; ni < 4; ++ni)
            acc[mi][ni] = __builtin_amdgcn_mfma_f32_16x16x32_bf16(af[mi], bfr[ni], acc[mi][ni], 0, 0, 0);
      }
    }
    __syncthreads();  // drains vmcnt (staging done) + all reads of cur complete
    cur ^= 1;
  }

  if (zz < 2) {
    unsigned short* C = (unsigned short*)(zz == 0 ? C0v : C1v);
#pragma unroll
    for (int mi = 0; mi < FM; ++mi)
#pragma unroll
      for (int ni = 0; ni < 4; ++ni) {
        int mbase = m0 + wr * WM + mi * 16 + (l >> 4) * 4;
        int n = n0 + wc * 64 + ni * 16 + lr;
#pragma unroll
        for (int r = 0; r < 4; ++r) {
          __bf16 v = (__bf16)acc[mi][ni][r];
          C[(size_t)(mbase + r) * 1024 + n] = *(unsigned short*)&v;
        }
      }
  } else {
    // V: compact LDS transpose [128][BM] (swizzled) -> coalesced [b,h,d,t] stores
    constexpr int RS = BM * 2;
    constexpr int TCH = BM / 8;
    constexpr int NIT = 128 * TCH / 256;
    char* Tb = (char*)SMEM;
#pragma unroll
    for (int mi = 0; mi < FM; ++mi)
#pragma unroll
      for (int ni = 0; ni < 4; ++ni) {
        int mb2 = wr * WM + mi * 16 + (l >> 4) * 4;
        int nl = wc * 64 + ni * 16 + lr;
        bf16x4 pk;
        pk[0] = (__bf16)acc[mi][ni][0]; pk[1] = (__bf16)acc[mi][ni][1];
        pk[2] = (__bf16)acc[mi][ni][2]; pk[3] = (__bf16)acc[mi][ni][3];
        *(bf16x4*)(Tb + ((nl * RS + mb2 * 2) ^ ((nl & 7) << 4))) = pk;
      }
    __syncthreads();
    unsigned short* C = (unsigned short*)C2v;
    int bb = m0 >> 10, tbase = m0 & 1023;
#pragma unroll
    for (int it = 0; it < NIT; ++it) {
      int ci = tid + 256 * it;
      int dl = ci / TCH, tc = ci % TCH;
      bf16x8 v = *(bf16x8*)(Tb + ((dl * RS + tc * 16) ^ ((dl & 7) << 4)));
      int n = n0 + dl, hh = n >> 6, dd = n & 63;
      *(bf16x8*)&C[((size_t)(bb * H_ + hh) * DH + dd) * T_ + tbase + tc * 8] = v;
    }
  }
}

// ---------------- out GEMM: 2-phase dbuf, BM=64 BN=64 -> 512 blocks, 32 KB LDS ----------------
__global__ __launch_bounds__(256) void out_gemm(const unsigned short* __restrict__ A,
    const unsigned short* __restrict__ Bw, float* __restrict__ C) {
  constexpr int K = 1024;
  constexpr int HALF = 128 * 64;
  __shared__ __attribute__((aligned(16))) unsigned short SMEM[2 * HALF];

  int m0 = blockIdx.x * 64, n0 = blockIdx.y * 64;
  int tid = threadIdx.x;
  int w = tid >> 6, l = tid & 63;
  int wr = w >> 1, wc = w & 1;
  int lr = l & 15, kg = l >> 4;

  f32x4 acc[2][2] = {};

  {
    unsigned short* As = SMEM;
    unsigned short* Bs = SMEM + 64 * 64;
#pragma unroll
    for (int i = 0; i < 2; ++i) {
      int ci = tid + 256 * i;
      int row = ci >> 3, c8 = (ci & 7) ^ (row & 7);
      gload16(A + (size_t)(m0 + row) * K + c8 * 8, As + ci * 8);
      gload16(Bw + (size_t)(n0 + row) * K + c8 * 8, Bs + ci * 8);
    }
  }
  __syncthreads();

  int cur = 0;
  for (int kt = 0; kt < K; kt += 64) {
    if (kt + 64 < K) {
      unsigned short* As = SMEM + (cur ^ 1) * HALF;
      unsigned short* Bs = As + 64 * 64;
      int ktn = kt + 64;
#pragma unroll
      for (int i = 0; i < 2; ++i) {
        int ci = tid + 256 * i;
        int row = ci >> 3, c8 = (ci & 7) ^ (row & 7);
        gload16(A + (size_t)(m0 + row) * K + ktn + c8 * 8, As + ci * 8);
        gload16(Bw + (size_t)(n0 + row) * K + ktn + c8 * 8, Bs + ci * 8);
      }
    }
    {
      unsigned short* As = SMEM + cur * HALF;
      unsigned short* Bs = As + 64 * 64;
#pragma unroll
      for (int kk = 0; kk < 2; ++kk) {
        int c8 = kk * 4 + kg;
        bf16x8 af[2], bfr[2];
#pragma unroll
        for (int mi = 0; mi < 2; ++mi) {
          int row = wr * 32 + mi * 16 + lr;
          af[mi] = *(bf16x8*)&As[row * 64 + ((c8 ^ (row & 7)) * 8)];
        }
#pragma unroll
        for (int ni = 0; ni < 2; ++ni) {
          int row = wc * 32 + ni * 16 + lr;
          bfr[ni] = *(bf16x8*)&Bs[row * 64 + ((c8 ^ (row & 7)) * 8)];
        }
#pragma unroll
        for (int mi = 0; mi < 2; ++mi)
#pragma unroll
          for (int ni = 0; ni < 2; ++ni)
            acc[mi][ni] = __builtin_amdgcn_mfma_f32_16x16x32_bf16(af[mi], bfr[ni], acc[mi][ni], 0, 0, 0);
      }
    }
    __syncthreads();
    cur ^= 1;
  }

#pragma unroll
  for (int mi = 0; mi < 2; ++mi)
#pragma unroll
    for (int ni = 0; ni < 2; ++ni) {
      int mbase = m0 + wr * 32 + mi * 16 + (l >> 4) * 4;
      int n = n0 + wc * 32 + ni * 16 + lr;
#pragma unroll
      for (int r = 0; r < 4; ++r)
        C[(size_t)(mbase + r) * 1024 + n] = acc[mi][ni][r];
    }
}

// ---------------- attention core: MFMA scores + MFMA PV, dual softmax, fused fa ----------------
// q,k: bf16 row-major [b*T][1024] (col = h*64+d). v: bf16 [b,h,d,t].
// Sf overlaid on KbL (dead after phase 1) -> 44.6 KB LDS -> 3 blocks/CU.
__global__ __launch_bounds__(512, 6) void attn_kernel(
    const unsigned short* __restrict__ qg, const unsigned short* __restrict__ kg_,
    const unsigned short* __restrict__ vg,
    const int* __restrict__ gidx_g, const float* __restrict__ gval_g,
    unsigned short* __restrict__ ctxb, float* __restrict__ fa) {
  int tid = threadIdx.x;
  int lid = blockIdx.x + 32 * blockIdx.y + 512 * blockIdx.z;
  int swz = (lid & 7) * 128 + (lid >> 3);          // bijective: 1024 % 8 == 0
  int b = swz >> 9, h = (swz >> 5) & 15;
  int t0 = (swz & 31) * 32;
  int lane = tid & 63, wv = tid >> 6;

  __shared__ __attribute__((aligned(16))) unsigned short QbL[32 * 64];
  __shared__ __attribute__((aligned(16))) unsigned short KbL[128 * 64];   // phase<=1: K tile; after: Sf f32[32][128]
  __shared__ __attribute__((aligned(16))) unsigned short VtL[64 * 128];
  __shared__ __attribute__((aligned(16))) unsigned short WbL[32 * 128];
  __shared__ float m_out_s[32], invdo_s[32], rowfac_s[32];
  __shared__ int   gidx_s[32];
  __shared__ float gval_s[32];
  float* Sfp = (float*)KbL;

  if (tid < 32) { gidx_s[tid] = gidx_g[b * NG + tid]; gval_s[tid] = gval_g[b * NG + tid]; }
  ((unsigned long long*)WbL)[tid] = 0ull;
  ((unsigned long long*)WbL)[tid + 512] = 0ull;
  __syncthreads();

  const unsigned short* qbh = qg + (size_t)(b * T_ + t0) * D_ + h * DH;
  const unsigned short* kbh = kg_ + (size_t)(b * T_) * D_ + h * DH;
  const unsigned short* vbh = vg + (size_t)(b * H_ + h) * DH * T_;

  if (tid < 256) {
    int r = tid >> 3, c8 = tid & 7;
    bf16x8 v = *(const bf16x8*)(qbh + (size_t)r * D_ + c8 * 8);
    *(bf16x8*)((char*)QbL + ((r * 128 + c8 * 16) ^ ((r & 7) << 4))) = v;
  }
#pragma unroll
  for (int it = 0; it < 2; ++it) {
    int fi = tid + it * 512;
    int r = fi >> 3, c8 = fi & 7;
    int col; bool valid;
    if (r < 96) { col = t0 - 32 + r; valid = (col >= 0 && col < T_); }
    else { int g = r - 96; valid = gval_s[g] > 0.f; col = valid ? gidx_s[g] : 0; }
    bf16x8 v = {};
    if (valid) v = *(const bf16x8*)(kbh + (size_t)col * D_ + c8 * 8);
    *(bf16x8*)((char*)KbL + ((r * 128 + c8 * 16) ^ ((r & 7) << 4))) = v;
  }
#pragma unroll
  for (int it = 0; it < 2; ++it) {
    int fi = tid + it * 512;
    if (fi < 768) {
      int d = fi / 12, rc = fi % 12;
      int cb = t0 - 32 + rc * 8;
      bf16x8 v = {};
      if (cb >= 0 && cb < T_) v = *(const bf16x8*)(vbh + d * T_ + cb);
      *(bf16x8*)((char*)VtL + ((d * 256 + rc * 16) ^ ((d & 7) << 4))) = v;
    }
  }
#pragma unroll
  for (int it = 0; it < 4; ++it) {
    int fi = tid + it * 512;
    int d = fi >> 5, g = fi & 31;
    unsigned short v = 0;
    if (gval_s[g] > 0.f) v = vbh[d * T_ + gidx_s[g]];
    *(unsigned short*)((char*)VtL + ((d * 256 + (96 + g) * 2) ^ ((d & 7) << 4))) = v;
  }
  __syncthreads();

  // phase 1: S = Q·K^T via MFMA (accs in regs; Sf written after barrier into KbL space)
  {
    int mt = wv & 1, nq = wv >> 1;
    int lrr = lane & 15, kgl = lane >> 4;
    int arow = mt * 16 + lrr;
    f32x4 acc0 = {}, acc1 = {};
#pragma unroll
    for (int s = 0; s < 2; ++s) {
      int c = s * 4 + kgl;
      bf16x8 a = *(bf16x8*)((char*)QbL + ((arow * 128 + c * 16) ^ ((arow & 7) << 4)));
      int br0 = nq * 32 + lrr, br1 = nq * 32 + 16 + lrr;
      bf16x8 b0 = *(bf16x8*)((char*)KbL + ((br0 * 128 + c * 16) ^ ((br0 & 7) << 4)));
      bf16x8 b1 = *(bf16x8*)((char*)KbL + ((br1 * 128 + c * 16) ^ ((br1 & 7) << 4)));
      acc0 = __builtin_amdgcn_mfma_f32_16x16x32_bf16(a, b0, acc0, 0, 0, 0);
      acc1 = __builtin_amdgcn_mfma_f32_16x16x32_bf16(a, b1, acc1, 0, 0, 0);
    }
    __syncthreads();  // all KbL reads done before Sf overlay writes
    int orow = mt * 16 + (lane >> 4) * 4;
#pragma unroll
    for (int i = 0; i < 4; ++i) {
      Sfp[SFIDX(orow + i, nq * 32 + lrr)] = acc0[i] * 0.125f;
      Sfp[SFIDX(orow + i, nq * 32 + 16 + lrr)] = acc1[i] * 0.125f;
    }
  }
  __syncthreads();

  // phase 2: per-row stats for both softmaxes
  {
    int r = tid >> 4, lg = tid & 15;
    int t_abs = t0 + r;
    int left = (t_abs - WND > 0) ? (t_abs - WND) : 0;
    int tmp = t_abs + WND + 1; if (tmp > T_) tmp = T_;
    int wl = tmp - left;
    float sv[8]; bool vld[8], vdd[8];
#pragma unroll
    for (int ii = 0; ii < 8; ++ii) {
      int c = lg + ii * 16;
      bool loc = (c >= r && c <= r + 64);
      bool glob = (c >= 96);
      float s = Sfp[SFIDX(r, c)];
      if (glob && !(gval_s[c - 96] > 0.f)) s = -1e9f;
      vld[ii] = loc || glob;
      vdd[ii] = loc ? ((c - r) < wl) : glob;
      sv[ii] = s;
    }
    float mo = -1e30f, md = -1e30f;
#pragma unroll
    for (int ii = 0; ii < 8; ++ii) {
      if (vld[ii]) mo = fmaxf(mo, sv[ii]);
      if (vdd[ii]) md = fmaxf(md, sv[ii]);
    }
#pragma unroll
    for (int o = 1; o < 16; o <<= 1) {
      mo = fmaxf(mo, __shfl_xor(mo, o, 16));
      md = fmaxf(md, __shfl_xor(md, o, 16));
    }
    float eo = 0.f, ed = 0.f;
#pragma unroll
    for (int ii = 0; ii < 8; ++ii) {
      if (vld[ii]) eo += __expf(sv[ii] - mo);
      if (vdd[ii]) ed += __expf(sv[ii] - md);
    }
#pragma unroll
    for (int o = 1; o < 16; o <<= 1) {
      eo += __shfl_xor(eo, o, 16);
      ed += __shfl_xor(ed, o, 16);
    }
    if (lg == 0) {
      m_out_s[r] = mo;
      invdo_s[r] = 1.f / eo;
      rowfac_s[r] = (eo / ed) * __expf(mo - md);
    }
  }
  __syncthreads();

  // phase 2b: scores -> out-path weights (f32 in Sf, bf16 in Wb)
  for (int idx = tid; idx < 32 * 97; idx += 512) {
    int t = idx / 97;
    int j = idx - t * 97;
    int cc = (j < KSZ) ? (t + j) : (j + 31);
    float s = Sfp[SFIDX(t, cc)];
    float wgt = __expf(s - m_out_s[t]) * invdo_s[t];
    Sfp[SFIDX(t, cc)] = wgt;
    *(unsigned short*)((char*)WbL + ((t * 256 + cc * 2) ^ ((t & 7) << 4))) = f2bf(wgt);
  }
  __syncthreads();

  // phase 3: ctx^T = V^T · W^T via MFMA
  {
    int mt = wv >> 1, nt = wv & 1;
    int lrr = lane & 15, kgl = lane >> 4;
    int arow = mt * 16 + lrr;
    int brow = nt * 16 + lrr;
    f32x4 acc = {};
#pragma unroll
    for (int s = 0; s < 4; ++s) {
      int c = s * 4 + kgl;
      bf16x8 a = *(bf16x8*)((char*)VtL + ((arow * 256 + c * 16) ^ ((arow & 7) << 4)));
      bf16x8 bb = *(bf16x8*)((char*)WbL + ((brow * 256 + c * 16) ^ ((brow & 7) << 4)));
      acc = __builtin_amdgcn_mfma_f32_16x16x32_bf16(a, bb, acc, 0, 0, 0);
    }
    int t = nt * 16 + lrr;
    int dbase = mt * 16 + (lane >> 4) * 4;
    u16x4 st;
    st.x = f2bf(acc[0]); st.y = f2bf(acc[1]); st.z = f2bf(acc[2]); st.w = f2bf(acc[3]);
    *(u16x4*)(ctxb + ((size_t)(b * T_ + t0 + t)) * D_ + h * DH + dbase) = st;
  }

  // phase 4: dense full_attn rows
  {
    int rp = tid >> 8;
    int c0 = (tid & 255) * 4;
    unsigned gm = 0;
#pragma unroll
    for (int g = 0; g < NG; ++g) {
      int gc = gidx_s[g];
      if (gval_s[g] > 0.f && gc >= c0 && gc < c0 + 4) gm |= (1u << g);
    }
#pragma unroll 2
    for (int rr = 0; rr < 16; ++rr) {
      int r = rr * 2 + rp;
      int t_abs = t0 + r;
      int left = (t_abs - WND > 0) ? (t_abs - WND) : 0;
      int tmp = t_abs + WND + 1; if (tmp > T_) tmp = T_;
      int wl = tmp - left;
      float rf = rowfac_s[r];
      f32x4 o = {0.f, 0.f, 0.f, 0.f};
      int jj0 = c0 - left;
      if (jj0 > -4 && jj0 < wl) {
#pragma unroll
        for (int e = 0; e < 4; ++e) {
          int jj = jj0 + e;
          if (jj >= 0 && jj < wl) o[e] = Sfp[SFIDX(r, r + jj)] * rf;
        }
      }
      if (gm) {
        unsigned mm = gm;
        while (mm) {
          int g = __ffs(mm) - 1; mm &= mm - 1;
          o[gidx_s[g] - c0] += Sfp[SFIDX(r, 96 + g)] * rf;
        }
      }
      float* dst = fa + (((size_t)(b * H_ + h) * T_) + t_abs) * T_ + c0;
      *(f32x4*)dst = o;
    }
  }
}

extern "C" void kernel_launch(void* const* d_in, const int* in_sizes, int n_in,
                              void* d_out, int out_size, void* d_ws, size_t ws_size,
                              hipStream_t stream) {
  const float* x   = (const float*)d_in[0];
  const int* gmask = (const int*)d_in[1];
  const float* wq  = (const float*)d_in[2];
  const float* wk  = (const float*)d_in[3];
  const float* wv  = (const float*)d_in[4];
  const float* wo  = (const float*)d_in[5];

  unsigned short* arena = (unsigned short*)d_ws;
  unsigned short* xb  = arena;                       // [2048][1024] bf16
  unsigned short* wqb = arena + 2 * 1048576;
  unsigned short* wkb = arena + 3 * 1048576;
  unsigned short* wvb = arena + 4 * 1048576;
  unsigned short* wob = arena + 5 * 1048576;
  unsigned short* qb   = arena + 6 * 1048576;        // [2048][1024] bf16
  unsigned short* kb   = arena + 8 * 1048576;
  unsigned short* vtb  = arena + 10 * 1048576;       // [b,h,d,t]
  unsigned short* ctxb = arena + 12 * 1048576;       // [2048][1024] bf16
  int*   gidx = (int*)(arena + 14 * 1048576);
  float* gval = (float*)(gidx + 64);

  float* outp = (float*)d_out;
  float* fa   = outp + 2097152;

  cvt_kernel<<<dim3(6145), dim3(256), 0, stream>>>(x, wq, wk, wv, wo, xb, gmask, gidx, gval);
  gemm128<64, 64><<<dim3(32, 8, 3), dim3(256), 0, stream>>>(xb, wqb, wkb, wvb, qb, kb, vtb);
  attn_kernel<<<dim3(32, 16, 2), dim3(512), 0, stream>>>(qb, kb, vtb, gidx, gval, ctxb, fa);
  out_gemm<<<dim3(32, 16), dim3(256), 0, stream>>>(ctxb, wob, outp);
}